// Round 20
// baseline (916.224 us; speedup 1.0000x reference)
//
#include <hip/hip_runtime.h>
#include <hip/hip_bf16.h>
#include <cstdint>

#define BB 2
#define TT 2048
#define DD 1024
#define HH 16
#define DHH 64
#define DFF 4096
#define LL 4
#define MM (BB*TT)   // 4096 rows
#define NT (TT/64)   // 32 key tiles

typedef __attribute__((ext_vector_type(8))) short short8v;
typedef __attribute__((ext_vector_type(4))) short short4v;
typedef __attribute__((ext_vector_type(4))) float floatx4;

typedef __attribute__((address_space(3))) void lds_void;
typedef const __attribute__((address_space(1))) void glb_void;

__device__ __forceinline__ void gload_lds16(const void* g, void* l) {
  __builtin_amdgcn_global_load_lds((glb_void*)g, (lds_void*)l, 16, 0, 0);
}

__device__ __forceinline__ float bf2f(short s) {
  union { unsigned u; float f; } v; v.u = ((unsigned)(unsigned short)s) << 16; return v.f;
}
__device__ __forceinline__ short f2bf(float f) {
  union { float f; unsigned u; } v; v.f = f;
  unsigned r = (v.u + 0x7fffu + ((v.u >> 16) & 1u)) >> 16;
  return (short)r;
}
__device__ __forceinline__ unsigned pack2bf(float a, float b) {
  __hip_bfloat162 h = __float22bfloat162_rn(make_float2(a, b));
  return *reinterpret_cast<unsigned*>(&h);
}
// raw v_exp_f32 (2^x), ~1ulp; inputs bounded in our uses
__device__ __forceinline__ float fexp2(float x) {
  float r; asm("v_exp_f32 %0, %1" : "=v"(r) : "v"(x)); return r;
}
__device__ __forceinline__ float max3f(float a, float b, float c) {
  float r; asm("v_max3_f32 %0, %1, %2, %3" : "=v"(r) : "v"(a), "v"(b), "v"(c)); return r;
}
// fast GELU (tanh form); |err| < 3e-3, validated R8-R19 (absmax 0.03125)
__device__ __forceinline__ float gelu_fast(float x) {
  const float u = x * x;
  const float w = fmaf(u, -0.10294537f, -2.302203f);
  const float t = fexp2(w * x);
  return x * __builtin_amdgcn_rcpf(1.f + t);
}

#define SCL2 0.18033688011112042f   // 0.125 * log2(e)
__device__ __forceinline__ short8v scale8(short8v v) {
  short8v r;
#pragma unroll
  for (int i = 0; i < 8; ++i) r[i] = f2bf(bf2f(v[i]) * SCL2);
  return r;
}

// ---------------- fp32 -> bf16 cast of one layer's 6 weight matrices into one buffer
#define SEG (DD*DD)              // 1048576
#define WTOT (4*SEG + 2*DFF*DD)  // 12582912
__global__ __launch_bounds__(256) void cast_layer(
    const float* __restrict__ wq, const float* __restrict__ wk,
    const float* __restrict__ wv, const float* __restrict__ wo,
    const float* __restrict__ f1, const float* __restrict__ f2,
    short* __restrict__ dst)
{
  const int i = (blockIdx.x * 256 + threadIdx.x) * 4;
  const float* src; int off;
  if      (i <     SEG) { src = wq; off = i; }
  else if (i < 2 * SEG) { src = wk; off = i - SEG; }
  else if (i < 3 * SEG) { src = wv; off = i - 2 * SEG; }
  else if (i < 4 * SEG) { src = wo; off = i - 3 * SEG; }
  else if (i < 4 * SEG + DFF * DD) { src = f1; off = i - 4 * SEG; }
  else { src = f2; off = i - 4 * SEG - DFF * DD; }
  const float4 v = *(const float4*)(src + off);
  short4v o; o[0] = f2bf(v.x); o[1] = f2bf(v.y); o[2] = f2bf(v.z); o[3] = f2bf(v.w);
  *(short4v*)(dst + i) = o;
}

// ================= 256x256 8-wave 4-phase GEMM (T2+T3+T4+T5) =================
// QKV=1: bias comes from 3 segment pointers (col-tile never straddles 1024-boundary)
template<int GELU, int QKV>
__global__ __launch_bounds__(512, 2) void gemm256(
    const short* __restrict__ A, const short* __restrict__ W,
    const float* __restrict__ b0, const float* __restrict__ b1,
    const float* __restrict__ b2, short* __restrict__ C,
    int M, int N, int K)
{
  __shared__ __align__(16) short lds[65536];
  const int t = threadIdx.x;
  const int lane = t & 63, wave = t >> 6;
  const int wm = wave >> 2, wn = wave & 3;
  const int l15 = lane & 15, lg = lane >> 4;

  const int nwg = gridDim.x * gridDim.y;
  const int bid0 = blockIdx.y * gridDim.x + blockIdx.x;
  const int q8 = nwg >> 3;
  const int lid = (bid0 & 7) * q8 + (bid0 >> 3);
  const int bx = lid % gridDim.x, by = lid / gridDim.x;

  const size_t abase = (size_t)by * 256 * K;
  const size_t wbase = (size_t)bx * 256 * K;

  floatx4 acc[8][4];
  floatx4 zero = {0.f, 0.f, 0.f, 0.f};
#pragma unroll
  for (int m = 0; m < 8; ++m)
#pragma unroll
    for (int n = 0; n < 4; ++n) acc[m][n] = zero;

#define STG_A(sl_, h_, u_) do {                                                \
    _Pragma("unroll")                                                          \
    for (int j_ = 0; j_ < 2; ++j_) {                                           \
      const int c_ = j_ * 512 + t, r_ = c_ >> 3;                               \
      const int kc_ = (c_ & 7) ^ (r_ & 7);                                     \
      gload_lds16(A + abase + (size_t)((h_) * 128 + r_) * K + (u_) * 64 + kc_ * 8, \
                  &lds[(sl_) * 16384 + (h_) * 8192 + (j_ * 512 + wave * 64) * 8]); \
    } } while (0)
#define STG_B(sl_, h_, u_) do {                                                \
    _Pragma("unroll")                                                          \
    for (int j_ = 0; j_ < 2; ++j_) {                                           \
      const int c_ = j_ * 512 + t, r_ = c_ >> 3;                               \
      const int kc_ = (c_ & 7) ^ (r_ & 7);                                     \
      gload_lds16(W + wbase + (size_t)((h_) * 128 + r_) * K + (u_) * 64 + kc_ * 8, \
                  &lds[32768 + (sl_) * 16384 + (h_) * 8192 + (j_ * 512 + wave * 64) * 8]); \
    } } while (0)

  const int NTK = K >> 6;
  STG_A(0, 0, 0); STG_A(0, 1, 0); STG_B(0, 0, 0); STG_B(0, 1, 0);

  for (int u = 0; u < NTK; ++u) {
    const int sl = u & 1, ns = sl ^ 1;
    const int aoff = sl * 16384 + wm * 8192;
    const int boff = 32768 + sl * 16384 + (wn >> 1) * 8192;
    short8v bfr[4][2];
#pragma unroll
    for (int p = 0; p < 4; ++p) {
      if (p == 0) {
        if (u + 1 < NTK) {
          STG_A(ns, 0, u + 1);
          asm volatile("s_waitcnt vmcnt(2)" ::: "memory");
        } else {
          asm volatile("s_waitcnt vmcnt(0)" ::: "memory");
        }
        __builtin_amdgcn_s_barrier();
#pragma unroll
        for (int n = 0; n < 4; ++n)
#pragma unroll
          for (int kk = 0; kk < 2; ++kk) {
            const int rl = (wn & 1) * 64 + n * 16 + l15;
            bfr[n][kk] = *(const short8v*)&lds[boff + rl * 64 + ((kk * 4 + lg) ^ (rl & 7)) * 8];
          }
      } else if (p == 1) { if (u + 1 < NTK) STG_A(ns, 1, u + 1); }
      else if (p == 2)   { if (u + 1 < NTK) STG_B(ns, 0, u + 1); }
      else               { if (u + 1 < NTK) STG_B(ns, 1, u + 1); }

      short8v af[2][2];
#pragma unroll
      for (int i = 0; i < 2; ++i)
#pragma unroll
        for (int kk = 0; kk < 2; ++kk) {
          const int rl = (2 * p + i) * 16 + l15;
          af[i][kk] = *(const short8v*)&lds[aoff + rl * 64 + ((kk * 4 + lg) ^ (rl & 7)) * 8];
        }
      // NOTE: no forced lgkmcnt(0) drain — compiler emits fine-grained waits
      __builtin_amdgcn_s_setprio(1);
#pragma unroll
      for (int kk = 0; kk < 2; ++kk)
#pragma unroll
        for (int i = 0; i < 2; ++i)
#pragma unroll
          for (int n = 0; n < 4; ++n)
            acc[2 * p + i][n] = __builtin_amdgcn_mfma_f32_16x16x32_bf16(
                af[i][kk], bfr[n][kk], acc[2 * p + i][n], 0, 0, 0);
      __builtin_amdgcn_s_setprio(0);
      __builtin_amdgcn_s_barrier();
    }
  }
#undef STG_A
#undef STG_B

  const float* bp;
  int cbase = bx * 256 + wn * 64;
  if (QKV) {
    const int seg = cbase >> 10;
    bp = (seg == 0) ? b0 : (seg == 1 ? b1 : b2);
    cbase -= seg << 10;
  } else {
    bp = b0;
  }
  float bv[4];
#pragma unroll
  for (int n = 0; n < 4; ++n)
    bv[n] = bp[cbase + n * 16 + l15];
#pragma unroll
  for (int m = 0; m < 8; ++m)
#pragma unroll
    for (int jj = 0; jj < 4; ++jj) {
      const int row = by * 256 + wm * 128 + m * 16 + lg * 4 + jj;
      short* cp = C + (size_t)row * N + bx * 256 + wn * 64 + l15;
#pragma unroll
      for (int n = 0; n < 4; ++n) {
        float v = acc[m][n][jj] + bv[n];
        if (GELU) v = gelu_fast(v);
        cp[n * 16] = f2bf(v);
      }
    }
}

// ====== 128x128 8-wave GEMM, 3-slot LDS, ONE barrier per K-tile (N=1024 shapes) ======
template<int GELU>
__global__ __launch_bounds__(512, 2) void gemm128(
    const short* __restrict__ A, const short* __restrict__ W,
    const float* __restrict__ bias, short* __restrict__ C,
    int M, int N, int K)
{
  __shared__ __align__(16) short lds[49152];  // A: 3 slots @0; B: 3 slots @24576
  const int t = threadIdx.x;
  const int lane = t & 63, wave = t >> 6;
  const int wm = wave >> 2, wn = wave & 3;
  const int l15 = lane & 15, lg = lane >> 4;

  const int nwg = gridDim.x * gridDim.y;
  const int bid0 = blockIdx.y * gridDim.x + blockIdx.x;
  const int q8 = nwg >> 3;
  const int lid = (bid0 & 7) * q8 + (bid0 >> 3);
  const int bx = lid % gridDim.x, by = lid / gridDim.x;

  const size_t abase = (size_t)by * 128 * K;
  const size_t wbase = (size_t)bx * 128 * K;

  floatx4 acc[4][2];
  floatx4 zero = {0.f, 0.f, 0.f, 0.f};
#pragma unroll
  for (int m = 0; m < 4; ++m)
#pragma unroll
    for (int n = 0; n < 2; ++n) acc[m][n] = zero;

#define STG128(sl_, u_) do {                                                   \
    _Pragma("unroll")                                                          \
    for (int j_ = 0; j_ < 2; ++j_) {                                           \
      const int c_ = j_ * 512 + t, r_ = c_ >> 3;                               \
      const int kc_ = (c_ & 7) ^ (r_ & 7);                                     \
      gload_lds16(A + abase + (size_t)r_ * K + (u_) * 64 + kc_ * 8,            \
                  &lds[(sl_) * 8192 + (j_ * 512 + wave * 64) * 8]);            \
      gload_lds16(W + wbase + (size_t)r_ * K + (u_) * 64 + kc_ * 8,            \
                  &lds[24576 + (sl_) * 8192 + (j_ * 512 + wave * 64) * 8]);    \
    } } while (0)

  const int NTK = K >> 6;
  STG128(0, 0);
  STG128(1, 1);

  for (int u = 0; u < NTK; ++u) {
    const int sl = u % 3;
    if (u + 1 < NTK) asm volatile("s_waitcnt vmcnt(4)" ::: "memory");
    else             asm volatile("s_waitcnt vmcnt(0)" ::: "memory");
    __builtin_amdgcn_s_barrier();
    if (u + 2 < NTK) STG128((u + 2) % 3, u + 2);

    short8v bfr[2][2], af[4][2];
#pragma unroll
    for (int n = 0; n < 2; ++n)
#pragma unroll
      for (int kk = 0; kk < 2; ++kk) {
        const int rl = wn * 32 + n * 16 + l15;
        bfr[n][kk] = *(const short8v*)&lds[24576 + sl * 8192 + rl * 64 + ((kk * 4 + lg) ^ (rl & 7)) * 8];
      }
#pragma unroll
    for (int m = 0; m < 4; ++m)
#pragma unroll
      for (int kk = 0; kk < 2; ++kk) {
        const int rl = wm * 32 + ((m & 1) * 16) + l15 + (m >> 1) * 64;
        af[m][kk] = *(const short8v*)&lds[sl * 8192 + rl * 64 + ((kk * 4 + lg) ^ (rl & 7)) * 8];
      }
    // NOTE: no forced lgkmcnt(0) drain — compiler emits fine-grained waits
    __builtin_amdgcn_s_setprio(1);
#pragma unroll
    for (int kk = 0; kk < 2; ++kk)
#pragma unroll
      for (int m = 0; m < 4; ++m)
#pragma unroll
        for (int n = 0; n < 2; ++n)
          acc[m][n] = __builtin_amdgcn_mfma_f32_16x16x32_bf16(af[m][kk], bfr[n][kk], acc[m][n], 0, 0, 0);
    __builtin_amdgcn_s_setprio(0);
  }
#undef STG128

  float bv[2];
#pragma unroll
  for (int n = 0; n < 2; ++n)
    bv[n] = bias[bx * 128 + wn * 32 + n * 16 + l15];
#pragma unroll
  for (int m = 0; m < 4; ++m)
#pragma unroll
    for (int jj = 0; jj < 4; ++jj) {
      const int row = by * 128 + wm * 32 + (m & 1) * 16 + (m >> 1) * 64 + lg * 4 + jj;
      short* cp = C + (size_t)row * N + bx * 128 + wn * 32 + l15;
#pragma unroll
      for (int n = 0; n < 2; ++n) {
        float v = acc[m][n][jj] + bv[n];
        if (GELU) v = gelu_fast(v);
        cp[n * 16] = f2bf(v);
      }
    }
}

// ---------------- V transpose per (b,h): qkv[.][2048 + h*64 + dh] -> vt[B][H][64][T]
__global__ __launch_bounds__(256) void transpose_v(
    const short* __restrict__ qkv, short* __restrict__ vt)
{
  __shared__ short tile[64][65];
  const int tb = blockIdx.x, h = blockIdx.y, b = blockIdx.z;
  const int t = threadIdx.x;
  const int r = t >> 2, c4 = (t & 3) * 16;
  const short* src = qkv + ((size_t)(b * TT + tb * 64 + r)) * 3072 + 2048 + h * 64 + c4;
#pragma unroll
  for (int i = 0; i < 16; ++i) tile[r][c4 + i] = src[i];
  __syncthreads();
  short* dst = vt + ((size_t)((b * HH + h) * 64 + r)) * TT + tb * 64 + c4;
#pragma unroll
  for (int i = 0; i < 16; ++i) dst[i] = tile[c4 + i][r];
}

// ---------------- flash attention (R19 champion): 1 block = 128 q-rows; 8 waves x
// 16 q-rows. Swapped QK^T, pre-scaled Q, raw v_exp, max3 tree, 2-slot KV dbuf +
// counted vmcnt, defer-max, XCD swizzle, block-uniform mask fast path.
#define PSTR 72
__global__ __launch_bounds__(512, 4) void flash_attn(
    const short* __restrict__ qkv, const short* __restrict__ vt,
    const int* __restrict__ mask, short* __restrict__ ctx)
{
  const int t = threadIdx.x;
  const int lane = t & 63, wave = t >> 6;
  const int l15 = lane & 15, lg = lane >> 4;

  const int bid0 = blockIdx.x + gridDim.x * (blockIdx.y + gridDim.y * blockIdx.z);
  const int lid = (bid0 & 7) * 64 + (bid0 >> 3);
  const int qb = lid & 15, h = (lid >> 4) & 15, b = lid >> 8;

  __shared__ __align__(16) short Ks[2][64 * 64];
  __shared__ __align__(16) short Vs[2][64 * 64];
  __shared__ __align__(16) short p_lds[8][16 * PSTR];
  __shared__ int allv_lds;
  short* prow = p_lds[wave];

  // block-uniform mask check: 512 threads x int4 cover all 2048 keys of batch b
  if (t == 0) allv_lds = 1;
  __syncthreads();
  {
    const int4 mv = *(const int4*)&mask[b * TT + t * 4];
    if (!(mv.x && mv.y && mv.z && mv.w)) allv_lds = 0;   // benign race: all writers store 0
  }
  __syncthreads();
  const bool allv = (allv_lds != 0);

  const short* qp = qkv + ((size_t)(b * TT + qb * 128 + wave * 16 + l15)) * 3072 + h * 64;
  const short8v qf0 = scale8(*(const short8v*)(qp + lg * 8));
  const short8v qf1 = scale8(*(const short8v*)(qp + 32 + lg * 8));

  const short* kbase = qkv + (size_t)b * TT * 3072 + 1024 + h * 64;
  const short* vtb   = vt + ((size_t)(b * HH + h)) * 64 * TT;

  const int srow = lane >> 3;
  const int scol = (lane & 7) ^ (srow & 7);

  float m_run = -3e30f, l_run = 0.f;
  floatx4 zero = {0.f, 0.f, 0.f, 0.f};
  floatx4 o[4];
#pragma unroll
  for (int n = 0; n < 4; ++n) o[n] = zero;

#define STAGE_KV(bufi, kb_) do {                                             \
    const int r_ = wave * 8 + srow;                                          \
    gload_lds16(kbase + (size_t)((kb_) * 64 + r_) * 3072 + scol * 8,         \
                &Ks[bufi][wave * 512]);                                      \
    gload_lds16(vtb + (size_t)r_ * TT + (kb_) * 64 + scol * 8,               \
                &Vs[bufi][wave * 512]);                                      \
  } while (0)

#define FLASH_LOOP(MASKED)                                                        \
  {                                                                               \
    STAGE_KV(0, 0);                                                               \
    int buf = 0;                                                                  \
    for (int kb = 0; kb < NT; ++kb) {                                             \
      if (kb + 1 < NT) {                                                          \
        STAGE_KV(buf ^ 1, kb + 1);                                                \
        asm volatile("s_waitcnt vmcnt(2)" ::: "memory");                          \
      } else {                                                                    \
        asm volatile("s_waitcnt vmcnt(0)" ::: "memory");                          \
      }                                                                           \
      __builtin_amdgcn_s_barrier();                                               \
                                                                                  \
      float cm[4][4];                                                             \
      if (MASKED) {                                                               \
        _Pragma("unroll")                                                         \
        for (int n = 0; n < 4; ++n) {                                             \
          const int4 mv = *(const int4*)&mask[b * TT + kb * 64 + n * 16 + lg * 4];\
          cm[n][0] = mv.x ? 0.f : -1.5e30f; cm[n][1] = mv.y ? 0.f : -1.5e30f;     \
          cm[n][2] = mv.z ? 0.f : -1.5e30f; cm[n][3] = mv.w ? 0.f : -1.5e30f;     \
        }                                                                         \
      }                                                                           \
                                                                                  \
      floatx4 s[4];                                                               \
      _Pragma("unroll")                                                           \
      for (int n = 0; n < 4; ++n) {                                               \
        const int row = n * 16 + l15;                                             \
        const int ch0 = lg ^ (row & 7);                                           \
        const int ch1 = (lg + 4) ^ (row & 7);                                     \
        const short8v kf0 = *(const short8v*)&Ks[buf][row * 64 + ch0 * 8];        \
        const short8v kf1 = *(const short8v*)&Ks[buf][row * 64 + ch1 * 8];        \
        floatx4 a = zero;                                                         \
        a = __builtin_amdgcn_mfma_f32_16x16x32_bf16(kf0, qf0, a, 0, 0, 0);        \
        a = __builtin_amdgcn_mfma_f32_16x16x32_bf16(kf1, qf1, a, 0, 0, 0);        \
        s[n] = a;                                                                 \
      }                                                                           \
      if (MASKED) {                                                               \
        _Pragma("unroll")                                                         \
        for (int n = 0; n < 4; ++n)                                               \
          _Pragma("unroll")                                                       \
          for (int jj = 0; jj < 4; ++jj) s[n][jj] += cm[n][jj];                   \
      }                                                                           \
                                                                                  \
      const float t0 = max3f(s[0][0], s[0][1], s[0][2]);                          \
      const float t1 = max3f(s[0][3], s[1][0], s[1][1]);                          \
      const float t2 = max3f(s[1][2], s[1][3], s[2][0]);                          \
      const float t3 = max3f(s[2][1], s[2][2], s[2][3]);                          \
      const float t4 = max3f(s[3][0], s[3][1], s[3][2]);                          \
      float mx = fmaxf(max3f(t0, t1, t2), max3f(t3, t4, s[3][3]));                \
      mx = fmaxf(mx, __shfl_xor(mx, 16, 64));                                     \
      mx = fmaxf(mx, __shfl_xor(mx, 32, 64));                                     \
                                                                                  \
      const bool defer = __all(mx - m_run <= 11.5f);                              \
      const float mnew = defer ? m_run : fmaxf(m_run, mx);                        \
      float ps[4];                                                                \
      _Pragma("unroll")                                                           \
      for (int n = 0; n < 4; ++n) {                                               \
        s[n][0] = fexp2(s[n][0] - mnew);                                          \
        s[n][1] = fexp2(s[n][1] - mnew);                                          \
        s[n][2] = fexp2(s[n][2] - mnew);                                          \
        s[n][3] = fexp2(s[n][3] - mnew);                                          \
        ps[n] = (s[n][0] + s[n][1]) + (s[n][2] + s[n][3]);                        \
      }                                                                           \
      float sum = (ps[0] + ps[1]) + (ps[2] + ps[3]);                              \
      sum += __shfl_xor(sum, 16, 64);                                             \
      sum += __shfl_xor(sum, 32, 64);                                             \
      if (defer) {                                                                \
        l_run += sum;                                                             \
      } else {                                                                    \
        const float al = fexp2(m_run - mnew);                                     \
        l_run = l_run * al + sum;                                                 \
        m_run = mnew;                                                             \
        float alo[4];                                                             \
        _Pragma("unroll")                                                         \
        for (int jj = 0; jj < 4; ++jj) alo[jj] = __shfl(al, lg * 4 + jj, 16);     \
        _Pragma("unroll")                                                         \
        for (int n = 0; n < 4; ++n)                                               \
          _Pragma("unroll")                                                       \
          for (int jj = 0; jj < 4; ++jj) o[n][jj] *= alo[jj];                     \
      }                                                                           \
                                                                                  \
      _Pragma("unroll")                                                           \
      for (int n = 0; n < 4; ++n) {                                               \
        const unsigned u0 = pack2bf(s[n][0], s[n][1]);                            \
        const unsigned u1 = pack2bf(s[n][2], s[n][3]);                            \
        *(uint2*)&prow[l15 * PSTR + n * 16 + lg * 4] = make_uint2(u0, u1);        \
      }                                                                           \
      const short8v pf0 = *(const short8v*)&prow[l15 * PSTR + lg * 8];            \
      const short8v pf1 = *(const short8v*)&prow[l15 * PSTR + 32 + lg * 8];       \
                                                                                  \
      _Pragma("unroll")                                                           \
      for (int n = 0; n < 4; ++n) {                                               \
        const int row = n * 16 + l15;                                             \
        const int ch0 = lg ^ (row & 7);                                           \
        const int ch1 = (lg + 4) ^ (row & 7);                                     \
        const short8v vf0 = *(const short8v*)&Vs[buf][row * 64 + ch0 * 8];        \
        const short8v vf1 = *(const short8v*)&Vs[buf][row * 64 + ch1 * 8];        \
        o[n] = __builtin_amdgcn_mfma_f32_16x16x32_bf16(pf0, vf0, o[n], 0, 0, 0);  \
        o[n] = __builtin_amdgcn_mfma_f32_16x16x32_bf16(pf1, vf1, o[n], 0, 0, 0);  \
      }                                                                           \
      asm volatile("" ::: "memory");                                              \
      __builtin_amdgcn_s_barrier();                                               \
      buf ^= 1;                                                                   \
    }                                                                             \
  }

  if (allv) FLASH_LOOP(0)
  else      FLASH_LOOP(1)
#undef FLASH_LOOP
#undef STAGE_KV

#pragma unroll
  for (int jj = 0; jj < 4; ++jj) {
    const float inv = 1.f / __shfl(l_run, lg * 4 + jj, 16);
    const int row = qb * 128 + wave * 16 + lg * 4 + jj;
#pragma unroll
    for (int n = 0; n < 4; ++n)
      ctx[((size_t)(b * TT + row)) * DD + h * 64 + n * 16 + l15] = f2bf(o[n][jj] * inv);
  }
}

// ---------------- fused residual-add + LayerNorm; fp32 residual stream, fp32 g/b
__global__ __launch_bounds__(256) void add_ln(
    const float* __restrict__ xres, const short* __restrict__ add,
    const float* __restrict__ g, const float* __restrict__ bb,
    float* __restrict__ outf, short* __restrict__ outb)
{
  const int row = blockIdx.x, t = threadIdx.x;
  const int lane = t & 63, wave = t >> 6;
  const float4 xv = *(const float4*)(xres + (size_t)row * DD + t * 4);
  float y[4] = { xv.x, xv.y, xv.z, xv.w };
  if (add) {
    const short4v av = *(const short4v*)(add + (size_t)row * DD + t * 4);
#pragma unroll
    for (int i = 0; i < 4; ++i) y[i] += bf2f(av[i]);
  }
  float s = y[0] + y[1] + y[2] + y[3];
  float ss = y[0]*y[0] + y[1]*y[1] + y[2]*y[2] + y[3]*y[3];
#pragma unroll
  for (int off = 32; off >= 1; off >>= 1) {
    s  += __shfl_xor(s, off, 64);
    ss += __shfl_xor(ss, off, 64);
  }
  __shared__ float red[2][4];
  if (lane == 0) { red[0][wave] = s; red[1][wave] = ss; }
  __syncthreads();
  s  = red[0][0] + red[0][1] + red[0][2] + red[0][3];
  ss = red[1][0] + red[1][1] + red[1][2] + red[1][3];
  const float mu = s * (1.f / DD);
  const float var = ss * (1.f / DD) - mu * mu;
  const float rs = rsqrtf(var + 1e-5f);
  const float4 gv = *(const float4*)(g + t * 4);
  const float4 bv = *(const float4*)(bb + t * 4);
  float o[4];
  o[0] = (y[0] - mu) * rs * gv.x + bv.x;
  o[1] = (y[1] - mu) * rs * gv.y + bv.y;
  o[2] = (y[2] - mu) * rs * gv.z + bv.z;
  o[3] = (y[3] - mu) * rs * gv.w + bv.w;
  if (outf) *(float4*)(outf + (size_t)row * DD + t * 4) = make_float4(o[0], o[1], o[2], o[3]);
  if (outb) {
    short4v ov;
#pragma unroll
    for (int i = 0; i < 4; ++i) ov[i] = f2bf(o[i]);
    *(short4v*)(outb + (size_t)row * DD + t * 4) = ov;
  }
}

// ---------------- x (fp32) -> xb (bf16) only; first add_ln reads x directly
__global__ __launch_bounds__(256) void cast_in(
    const float* __restrict__ x, short* __restrict__ xb)
{
  const int i = (blockIdx.x * 256 + threadIdx.x) * 4;
  const float4 v = *(const float4*)(x + i);
  short4v o; o[0] = f2bf(v.x); o[1] = f2bf(v.y); o[2] = f2bf(v.z); o[3] = f2bf(v.w);
  *(short4v*)(xb + i) = o;
}

extern "C" void kernel_launch(void* const* d_in, const int* in_sizes, int n_in,
                              void* d_out, int out_size, void* d_ws, size_t ws_size,
                              hipStream_t stream) {
  const float* x   = (const float*)d_in[0];
  const int* mask  = (const int*)d_in[1];
  const float* Wq  = (const float*)d_in[2];
  const float* bq  = (const float*)d_in[3];
  const float* Wk  = (const float*)d_in[4];
  const float* bk  = (const float*)d_in[5];
  const float* Wv  = (const float*)d_in[6];
  const float* bv  = (const float*)d_in[7];
  const float* Wo  = (const float*)d_in[8];
  const float* bo  = (const float*)d_in[9];
  const float* f1w = (const float*)d_in[10];
  const float* f1b = (const float*)d_in[11];
  const float* f2w = (const float*)d_in[12];
  const float* f2b = (const float*)d_in[13];
  const float* l1g = (const float*)d_in[14];
  const float* l1b = (const float*)d_in[15];
  const float* l2g = (const float*)d_in[16];
  const float* l2b = (const float*)d_in[17];
  const float* lfg = (const float*)d_in[18];
  const float* lfb = (const float*)d_in[19];
  float* out = (float*)d_out;   // reference output dtype is float32

  char* ws = (char*)d_ws;
  const size_t MB = 1u << 20;
  float* xf   = (float*)(ws);              // 0-16  fp32 residual stream
  short* xb   = (short*)(ws + 16 * MB);    // 16-24 bf16 x
  short* qkv  = (short*)(ws + 24 * MB);    // 24-48 fused QKV [4096][3072]
  short* vt_  = (short*)(ws + 48 * MB);    // 48-56 V^T
  short* ctx  = (short*)(ws + 56 * MB);    // 56-64 attention context
  short* tmp  = (short*)(ws + 64 * MB);    // 64-72 attn_out / ff_out
  short* wbuf = (short*)(ws + 72 * MB);    // 72-97.2 layer weights (bf16)
  short* hb   = qkv;                       // FFN hidden 24-56MB (qkv/vt dead)

  cast_in<<<(MM * DD) / (256 * 4), 256, 0, stream>>>(x, xb);

  for (int l = 0; l < LL; ++l) {
    cast_layer<<<WTOT / (256 * 4), 256, 0, stream>>>(
        Wq + (size_t)l * SEG, Wk + (size_t)l * SEG, Wv + (size_t)l * SEG, Wo + (size_t)l * SEG,
        f1w + (size_t)l * DFF * DD, f2w + (size_t)l * DD * DFF, wbuf);
    const short* wqkv_b = wbuf;                       // [3072][1024]
    const short* wo_b   = wbuf + 3 * SEG;
    const short* f1_b   = wbuf + 4 * SEG;
    const short* f2_b   = wbuf + 4 * SEG + DFF * DD;

    gemm256<0,1><<<dim3(3072 / 256, MM / 256), 512, 0, stream>>>(
        xb, wqkv_b, bq + l * DD, bk + l * DD, bv + l * DD, qkv, MM, 3072, DD);
    transpose_v<<<dim3(TT / 64, HH, BB), 256, 0, stream>>>(qkv, vt_);
    flash_attn<<<dim3(TT / 128, HH, BB), 512, 0, stream>>>(qkv, vt_, mask, ctx);
    gemm128<0><<<dim3(DD / 128, MM / 128), 512, 0, stream>>>(ctx, wo_b, bo + l * DD, tmp, MM, DD, DD);
    add_ln<<<MM, 256, 0, stream>>>(l == 0 ? x : xf, tmp, l1g + l * DD, l1b + l * DD, xf, xb);
    gemm256<1,0><<<dim3(DFF / 256, MM / 256), 512, 0, stream>>>(
        xb, f1_b, f1b + l * DFF, nullptr, nullptr, hb, MM, DFF, DD);
    gemm128<0><<<dim3(DD / 128, MM / 128), 512, 0, stream>>>(hb, f2_b, f2b + l * DD, tmp, MM, DD, DFF);
    add_ln<<<MM, 256, 0, stream>>>(xf, tmp, l2g + l * DD, l2b + l * DD, xf, xb);
  }
  add_ln<<<MM, 256, 0, stream>>>(xf, nullptr, lfg, lfb, out, nullptr);
}

// Round 21
// 910.513 us; speedup vs baseline: 1.0063x; 1.0063x over previous
//
#include <hip/hip_runtime.h>
#include <hip/hip_bf16.h>
#include <cstdint>

#define BB 2
#define TT 2048
#define DD 1024
#define HH 16
#define DHH 64
#define DFF 4096
#define LL 4
#define MM (BB*TT)   // 4096 rows
#define NT (TT/64)   // 32 key tiles

typedef __attribute__((ext_vector_type(8))) short short8v;
typedef __attribute__((ext_vector_type(4))) short short4v;
typedef __attribute__((ext_vector_type(4))) float floatx4;

typedef __attribute__((address_space(3))) void lds_void;
typedef const __attribute__((address_space(1))) void glb_void;

__device__ __forceinline__ void gload_lds16(const void* g, void* l) {
  __builtin_amdgcn_global_load_lds((glb_void*)g, (lds_void*)l, 16, 0, 0);
}

__device__ __forceinline__ float bf2f(short s) {
  union { unsigned u; float f; } v; v.u = ((unsigned)(unsigned short)s) << 16; return v.f;
}
__device__ __forceinline__ short f2bf(float f) {
  union { float f; unsigned u; } v; v.f = f;
  unsigned r = (v.u + 0x7fffu + ((v.u >> 16) & 1u)) >> 16;
  return (short)r;
}
__device__ __forceinline__ unsigned pack2bf(float a, float b) {
  __hip_bfloat162 h = __float22bfloat162_rn(make_float2(a, b));
  return *reinterpret_cast<unsigned*>(&h);
}
// raw v_exp_f32 (2^x), ~1ulp; inputs bounded in our uses
__device__ __forceinline__ float fexp2(float x) {
  float r; asm("v_exp_f32 %0, %1" : "=v"(r) : "v"(x)); return r;
}
__device__ __forceinline__ float max3f(float a, float b, float c) {
  float r; asm("v_max3_f32 %0, %1, %2, %3" : "=v"(r) : "v"(a), "v"(b), "v"(c)); return r;
}
// fast GELU (tanh form); |err| < 3e-3, validated R8-R20 (absmax 0.03125)
__device__ __forceinline__ float gelu_fast(float x) {
  const float u = x * x;
  const float w = fmaf(u, -0.10294537f, -2.302203f);
  const float t = fexp2(w * x);
  return x * __builtin_amdgcn_rcpf(1.f + t);
}

#define SCL2 0.18033688011112042f   // 0.125 * log2(e)
__device__ __forceinline__ short8v scale8(short8v v) {
  short8v r;
#pragma unroll
  for (int i = 0; i < 8; ++i) r[i] = f2bf(bf2f(v[i]) * SCL2);
  return r;
}

// ---------------- fp32 -> bf16 cast of one layer's 6 weight matrices into one buffer
#define SEG (DD*DD)              // 1048576
#define WTOT (4*SEG + 2*DFF*DD)  // 12582912
__global__ __launch_bounds__(256) void cast_layer(
    const float* __restrict__ wq, const float* __restrict__ wk,
    const float* __restrict__ wv, const float* __restrict__ wo,
    const float* __restrict__ f1, const float* __restrict__ f2,
    short* __restrict__ dst)
{
  const int i = (blockIdx.x * 256 + threadIdx.x) * 4;
  const float* src; int off;
  if      (i <     SEG) { src = wq; off = i; }
  else if (i < 2 * SEG) { src = wk; off = i - SEG; }
  else if (i < 3 * SEG) { src = wv; off = i - 2 * SEG; }
  else if (i < 4 * SEG) { src = wo; off = i - 3 * SEG; }
  else if (i < 4 * SEG + DFF * DD) { src = f1; off = i - 4 * SEG; }
  else { src = f2; off = i - 4 * SEG - DFF * DD; }
  const float4 v = *(const float4*)(src + off);
  short4v o; o[0] = f2bf(v.x); o[1] = f2bf(v.y); o[2] = f2bf(v.z); o[3] = f2bf(v.w);
  *(short4v*)(dst + i) = o;
}

// ================= 256x256 8-wave 4-phase GEMM (T2+T3+T4+T5) =================
// QKV=1: bias comes from 3 segment pointers (col-tile never straddles 1024-boundary)
template<int GELU, int QKV>
__global__ __launch_bounds__(512, 2) void gemm256(
    const short* __restrict__ A, const short* __restrict__ W,
    const float* __restrict__ b0, const float* __restrict__ b1,
    const float* __restrict__ b2, short* __restrict__ C,
    int M, int N, int K)
{
  __shared__ __align__(16) short lds[65536];
  const int t = threadIdx.x;
  const int lane = t & 63, wave = t >> 6;
  const int wm = wave >> 2, wn = wave & 3;
  const int l15 = lane & 15, lg = lane >> 4;

  const int nwg = gridDim.x * gridDim.y;
  const int bid0 = blockIdx.y * gridDim.x + blockIdx.x;
  const int q8 = nwg >> 3;
  const int lid = (bid0 & 7) * q8 + (bid0 >> 3);
  const int bx = lid % gridDim.x, by = lid / gridDim.x;

  const size_t abase = (size_t)by * 256 * K;
  const size_t wbase = (size_t)bx * 256 * K;

  floatx4 acc[8][4];
  floatx4 zero = {0.f, 0.f, 0.f, 0.f};
#pragma unroll
  for (int m = 0; m < 8; ++m)
#pragma unroll
    for (int n = 0; n < 4; ++n) acc[m][n] = zero;

#define STG_A(sl_, h_, u_) do {                                                \
    _Pragma("unroll")                                                          \
    for (int j_ = 0; j_ < 2; ++j_) {                                           \
      const int c_ = j_ * 512 + t, r_ = c_ >> 3;                               \
      const int kc_ = (c_ & 7) ^ (r_ & 7);                                     \
      gload_lds16(A + abase + (size_t)((h_) * 128 + r_) * K + (u_) * 64 + kc_ * 8, \
                  &lds[(sl_) * 16384 + (h_) * 8192 + (j_ * 512 + wave * 64) * 8]); \
    } } while (0)
#define STG_B(sl_, h_, u_) do {                                                \
    _Pragma("unroll")                                                          \
    for (int j_ = 0; j_ < 2; ++j_) {                                           \
      const int c_ = j_ * 512 + t, r_ = c_ >> 3;                               \
      const int kc_ = (c_ & 7) ^ (r_ & 7);                                     \
      gload_lds16(W + wbase + (size_t)((h_) * 128 + r_) * K + (u_) * 64 + kc_ * 8, \
                  &lds[32768 + (sl_) * 16384 + (h_) * 8192 + (j_ * 512 + wave * 64) * 8]); \
    } } while (0)

  const int NTK = K >> 6;
  STG_A(0, 0, 0); STG_A(0, 1, 0); STG_B(0, 0, 0); STG_B(0, 1, 0);

  for (int u = 0; u < NTK; ++u) {
    const int sl = u & 1, ns = sl ^ 1;
    const int aoff = sl * 16384 + wm * 8192;
    const int boff = 32768 + sl * 16384 + (wn >> 1) * 8192;
    short8v bfr[4][2];
#pragma unroll
    for (int p = 0; p < 4; ++p) {
      if (p == 0) {
        if (u + 1 < NTK) {
          STG_A(ns, 0, u + 1);
          asm volatile("s_waitcnt vmcnt(2)" ::: "memory");
        } else {
          asm volatile("s_waitcnt vmcnt(0)" ::: "memory");
        }
        __builtin_amdgcn_s_barrier();
#pragma unroll
        for (int n = 0; n < 4; ++n)
#pragma unroll
          for (int kk = 0; kk < 2; ++kk) {
            const int rl = (wn & 1) * 64 + n * 16 + l15;
            bfr[n][kk] = *(const short8v*)&lds[boff + rl * 64 + ((kk * 4 + lg) ^ (rl & 7)) * 8];
          }
      } else if (p == 1) { if (u + 1 < NTK) STG_A(ns, 1, u + 1); }
      else if (p == 2)   { if (u + 1 < NTK) STG_B(ns, 0, u + 1); }
      else               { if (u + 1 < NTK) STG_B(ns, 1, u + 1); }

      short8v af[2][2];
#pragma unroll
      for (int i = 0; i < 2; ++i)
#pragma unroll
        for (int kk = 0; kk < 2; ++kk) {
          const int rl = (2 * p + i) * 16 + l15;
          af[i][kk] = *(const short8v*)&lds[aoff + rl * 64 + ((kk * 4 + lg) ^ (rl & 7)) * 8];
        }
      asm volatile("s_waitcnt lgkmcnt(0)" ::: "memory");
      __builtin_amdgcn_s_setprio(1);
#pragma unroll
      for (int kk = 0; kk < 2; ++kk)
#pragma unroll
        for (int i = 0; i < 2; ++i)
#pragma unroll
          for (int n = 0; n < 4; ++n)
            acc[2 * p + i][n] = __builtin_amdgcn_mfma_f32_16x16x32_bf16(
                af[i][kk], bfr[n][kk], acc[2 * p + i][n], 0, 0, 0);
      __builtin_amdgcn_s_setprio(0);
      __builtin_amdgcn_s_barrier();
    }
  }
#undef STG_A
#undef STG_B

  const float* bp;
  int cbase = bx * 256 + wn * 64;
  if (QKV) {
    const int seg = cbase >> 10;
    bp = (seg == 0) ? b0 : (seg == 1 ? b1 : b2);
    cbase -= seg << 10;
  } else {
    bp = b0;
  }
  float bv[4];
#pragma unroll
  for (int n = 0; n < 4; ++n)
    bv[n] = bp[cbase + n * 16 + l15];
#pragma unroll
  for (int m = 0; m < 8; ++m)
#pragma unroll
    for (int jj = 0; jj < 4; ++jj) {
      const int row = by * 256 + wm * 128 + m * 16 + lg * 4 + jj;
      short* cp = C + (size_t)row * N + bx * 256 + wn * 64 + l15;
#pragma unroll
      for (int n = 0; n < 4; ++n) {
        float v = acc[m][n][jj] + bv[n];
        if (GELU) v = gelu_fast(v);
        cp[n * 16] = f2bf(v);
      }
    }
}

// ====== 128x128 8-wave GEMM, 3-slot LDS, ONE barrier per K-tile (N=1024 shapes) ======
template<int GELU>
__global__ __launch_bounds__(512, 2) void gemm128(
    const short* __restrict__ A, const short* __restrict__ W,
    const float* __restrict__ bias, short* __restrict__ C,
    int M, int N, int K)
{
  __shared__ __align__(16) short lds[49152];  // A: 3 slots @0; B: 3 slots @24576
  const int t = threadIdx.x;
  const int lane = t & 63, wave = t >> 6;
  const int wm = wave >> 2, wn = wave & 3;
  const int l15 = lane & 15, lg = lane >> 4;

  const int nwg = gridDim.x * gridDim.y;
  const int bid0 = blockIdx.y * gridDim.x + blockIdx.x;
  const int q8 = nwg >> 3;
  const int lid = (bid0 & 7) * q8 + (bid0 >> 3);
  const int bx = lid % gridDim.x, by = lid / gridDim.x;

  const size_t abase = (size_t)by * 128 * K;
  const size_t wbase = (size_t)bx * 128 * K;

  floatx4 acc[4][2];
  floatx4 zero = {0.f, 0.f, 0.f, 0.f};
#pragma unroll
  for (int m = 0; m < 4; ++m)
#pragma unroll
    for (int n = 0; n < 2; ++n) acc[m][n] = zero;

#define STG128(sl_, u_) do {                                                   \
    _Pragma("unroll")                                                          \
    for (int j_ = 0; j_ < 2; ++j_) {                                           \
      const int c_ = j_ * 512 + t, r_ = c_ >> 3;                               \
      const int kc_ = (c_ & 7) ^ (r_ & 7);                                     \
      gload_lds16(A + abase + (size_t)r_ * K + (u_) * 64 + kc_ * 8,            \
                  &lds[(sl_) * 8192 + (j_ * 512 + wave * 64) * 8]);            \
      gload_lds16(W + wbase + (size_t)r_ * K + (u_) * 64 + kc_ * 8,            \
                  &lds[24576 + (sl_) * 8192 + (j_ * 512 + wave * 64) * 8]);    \
    } } while (0)

  const int NTK = K >> 6;
  STG128(0, 0);
  STG128(1, 1);

  for (int u = 0; u < NTK; ++u) {
    const int sl = u % 3;
    if (u + 1 < NTK) asm volatile("s_waitcnt vmcnt(4)" ::: "memory");
    else             asm volatile("s_waitcnt vmcnt(0)" ::: "memory");
    __builtin_amdgcn_s_barrier();
    if (u + 2 < NTK) STG128((u + 2) % 3, u + 2);

    short8v bfr[2][2], af[4][2];
#pragma unroll
    for (int n = 0; n < 2; ++n)
#pragma unroll
      for (int kk = 0; kk < 2; ++kk) {
        const int rl = wn * 32 + n * 16 + l15;
        bfr[n][kk] = *(const short8v*)&lds[24576 + sl * 8192 + rl * 64 + ((kk * 4 + lg) ^ (rl & 7)) * 8];
      }
#pragma unroll
    for (int m = 0; m < 4; ++m)
#pragma unroll
      for (int kk = 0; kk < 2; ++kk) {
        const int rl = wm * 32 + ((m & 1) * 16) + l15 + (m >> 1) * 64;
        af[m][kk] = *(const short8v*)&lds[sl * 8192 + rl * 64 + ((kk * 4 + lg) ^ (rl & 7)) * 8];
      }
    asm volatile("s_waitcnt lgkmcnt(0)" ::: "memory");
    __builtin_amdgcn_s_setprio(1);
#pragma unroll
    for (int kk = 0; kk < 2; ++kk)
#pragma unroll
      for (int m = 0; m < 4; ++m)
#pragma unroll
        for (int n = 0; n < 2; ++n)
          acc[m][n] = __builtin_amdgcn_mfma_f32_16x16x32_bf16(af[m][kk], bfr[n][kk], acc[m][n], 0, 0, 0);
    __builtin_amdgcn_s_setprio(0);
  }
#undef STG128

  float bv[2];
#pragma unroll
  for (int n = 0; n < 2; ++n)
    bv[n] = bias[bx * 128 + wn * 32 + n * 16 + l15];
#pragma unroll
  for (int m = 0; m < 4; ++m)
#pragma unroll
    for (int jj = 0; jj < 4; ++jj) {
      const int row = by * 128 + wm * 32 + (m & 1) * 16 + (m >> 1) * 64 + lg * 4 + jj;
      short* cp = C + (size_t)row * N + bx * 128 + wn * 32 + l15;
#pragma unroll
      for (int n = 0; n < 2; ++n) {
        float v = acc[m][n][jj] + bv[n];
        if (GELU) v = gelu_fast(v);
        cp[n * 16] = f2bf(v);
      }
    }
}

// ---------------- V transpose per (b,h): qkv[.][2048 + h*64 + dh] -> vt[B][H][64][T]
__global__ __launch_bounds__(256) void transpose_v(
    const short* __restrict__ qkv, short* __restrict__ vt)
{
  __shared__ short tile[64][65];
  const int tb = blockIdx.x, h = blockIdx.y, b = blockIdx.z;
  const int t = threadIdx.x;
  const int r = t >> 2, c4 = (t & 3) * 16;
  const short* src = qkv + ((size_t)(b * TT + tb * 64 + r)) * 3072 + 2048 + h * 64 + c4;
#pragma unroll
  for (int i = 0; i < 16; ++i) tile[r][c4 + i] = src[i];
  __syncthreads();
  short* dst = vt + ((size_t)((b * HH + h) * 64 + r)) * TT + tb * 64 + c4;
#pragma unroll
  for (int i = 0; i < 16; ++i) dst[i] = tile[c4 + i][r];
}

// ---------------- flash attention (R19 champion): 1 block = 128 q-rows; 8 waves x
// 16 q-rows. Swapped QK^T, pre-scaled Q, raw v_exp, max3 tree, 2-slot KV dbuf +
// counted vmcnt, defer-max, XCD swizzle, block-uniform mask fast path.
#define PSTR 72
__global__ __launch_bounds__(512, 4) void flash_attn(
    const short* __restrict__ qkv, const short* __restrict__ vt,
    const int* __restrict__ mask, short* __restrict__ ctx)
{
  const int t = threadIdx.x;
  const int lane = t & 63, wave = t >> 6;
  const int l15 = lane & 15, lg = lane >> 4;

  const int bid0 = blockIdx.x + gridDim.x * (blockIdx.y + gridDim.y * blockIdx.z);
  const int lid = (bid0 & 7) * 64 + (bid0 >> 3);
  const int qb = lid & 15, h = (lid >> 4) & 15, b = lid >> 8;

  __shared__ __align__(16) short Ks[2][64 * 64];
  __shared__ __align__(16) short Vs[2][64 * 64];
  __shared__ __align__(16) short p_lds[8][16 * PSTR];
  __shared__ int allv_lds;
  short* prow = p_lds[wave];

  // block-uniform mask check: 512 threads x int4 cover all 2048 keys of batch b
  if (t == 0) allv_lds = 1;
  __syncthreads();
  {
    const int4 mv = *(const int4*)&mask[b * TT + t * 4];
    if (!(mv.x && mv.y && mv.z && mv.w)) allv_lds = 0;   // benign race: all writers store 0
  }
  __syncthreads();
  const bool allv = (allv_lds != 0);

  const short* qp = qkv + ((size_t)(b * TT + qb * 128 + wave * 16 + l15)) * 3072 + h * 64;
  const short8v qf0 = scale8(*(const short8v*)(qp + lg * 8));
  const short8v qf1 = scale8(*(const short8v*)(qp + 32 + lg * 8));

  const short* kbase = qkv + (size_t)b * TT * 3072 + 1024 + h * 64;
  const short* vtb   = vt + ((size_t)(b * HH + h)) * 64 * TT;

  const int srow = lane >> 3;
  const int scol = (lane & 7) ^ (srow & 7);

  float m_run = -3e30f, l_run = 0.f;
  floatx4 zero = {0.f, 0.f, 0.f, 0.f};
  floatx4 o[4];
#pragma unroll
  for (int n = 0; n < 4; ++n) o[n] = zero;

#define STAGE_KV(bufi, kb_) do {                                             \
    const int r_ = wave * 8 + srow;                                          \
    gload_lds16(kbase + (size_t)((kb_) * 64 + r_) * 3072 + scol * 8,         \
                &Ks[bufi][wave * 512]);                                      \
    gload_lds16(vtb + (size_t)r_ * TT + (kb_) * 64 + scol * 8,               \
                &Vs[bufi][wave * 512]);                                      \
  } while (0)

#define FLASH_LOOP(MASKED)                                                        \
  {                                                                               \
    STAGE_KV(0, 0);                                                               \
    int buf = 0;                                                                  \
    for (int kb = 0; kb < NT; ++kb) {                                             \
      if (kb + 1 < NT) {                                                          \
        STAGE_KV(buf ^ 1, kb + 1);                                                \
        asm volatile("s_waitcnt vmcnt(2)" ::: "memory");                          \
      } else {                                                                    \
        asm volatile("s_waitcnt vmcnt(0)" ::: "memory");                          \
      }                                                                           \
      __builtin_amdgcn_s_barrier();                                               \
                                                                                  \
      float cm[4][4];                                                             \
      if (MASKED) {                                                               \
        _Pragma("unroll")                                                         \
        for (int n = 0; n < 4; ++n) {                                             \
          const int4 mv = *(const int4*)&mask[b * TT + kb * 64 + n * 16 + lg * 4];\
          cm[n][0] = mv.x ? 0.f : -1.5e30f; cm[n][1] = mv.y ? 0.f : -1.5e30f;     \
          cm[n][2] = mv.z ? 0.f : -1.5e30f; cm[n][3] = mv.w ? 0.f : -1.5e30f;     \
        }                                                                         \
      }                                                                           \
                                                                                  \
      floatx4 s[4];                                                               \
      _Pragma("unroll")                                                           \
      for (int n = 0; n < 4; ++n) {                                               \
        const int row = n * 16 + l15;                                             \
        const int ch0 = lg ^ (row & 7);                                           \
        const int ch1 = (lg + 4) ^ (row & 7);                                     \
        const short8v kf0 = *(const short8v*)&Ks[buf][row * 64 + ch0 * 8];        \
        const short8v kf1 = *(const short8v*)&Ks[buf][row * 64 + ch1 * 8];        \
        floatx4 a = zero;                                                         \
        a = __builtin_amdgcn_mfma_f32_16x16x32_bf16(kf0, qf0, a, 0, 0, 0);        \
        a = __builtin_amdgcn_mfma_f32_16x16x32_bf16(kf1, qf1, a, 0, 0, 0);        \
        s[n] = a;                                                                 \
      }                                                                           \
      if (MASKED) {                                                               \
        _Pragma("unroll")                                                         \
        for (int n = 0; n < 4; ++n)                                               \
          _Pragma("unroll")                                                       \
          for (int jj = 0; jj < 4; ++jj) s[n][jj] += cm[n][jj];                   \
      }                                                                           \
                                                                                  \
      const float t0 = max3f(s[0][0], s[0][1], s[0][2]);                          \
      const float t1 = max3f(s[0][3], s[1][0], s[1][1]);                          \
      const float t2 = max3f(s[1][2], s[1][3], s[2][0]);                          \
      const float t3 = max3f(s[2][1], s[2][2], s[2][3]);                          \
      const float t4 = max3f(s[3][0], s[3][1], s[3][2]);                          \
      float mx = fmaxf(max3f(t0, t1, t2), max3f(t3, t4, s[3][3]));                \
      mx = fmaxf(mx, __shfl_xor(mx, 16, 64));                                     \
      mx = fmaxf(mx, __shfl_xor(mx, 32, 64));                                     \
                                                                                  \
      const bool defer = __all(mx - m_run <= 11.5f);                              \
      const float mnew = defer ? m_run : fmaxf(m_run, mx);                        \
      float ps[4];                                                                \
      _Pragma("unroll")                                                           \
      for (int n = 0; n < 4; ++n) {                                               \
        s[n][0] = fexp2(s[n][0] - mnew);                                          \
        s[n][1] = fexp2(s[n][1] - mnew);                                          \
        s[n][2] = fexp2(s[n][2] - mnew);                                          \
        s[n][3] = fexp2(s[n][3] - mnew);                                          \
        ps[n] = (s[n][0] + s[n][1]) + (s[n][2] + s[n][3]);                        \
      }                                                                           \
      float sum = (ps[0] + ps[1]) + (ps[2] + ps[3]);                              \
      sum += __shfl_xor(sum, 16, 64);                                             \
      sum += __shfl_xor(sum, 32, 64);                                             \
      if (defer) {                                                                \
        l_run += sum;                                                             \
      } else {                                                                    \
        const float al = fexp2(m_run - mnew);                                     \
        l_run = l_run * al + sum;                                                 \
        m_run = mnew;                                                             \
        float alo[4];                                                             \
        _Pragma("unroll")                                                         \
        for (int jj = 0; jj < 4; ++jj) alo[jj] = __shfl(al, lg * 4 + jj, 16);     \
        _Pragma("unroll")                                                         \
        for (int n = 0; n < 4; ++n)                                               \
          _Pragma("unroll")                                                       \
          for (int jj = 0; jj < 4; ++jj) o[n][jj] *= alo[jj];                     \
      }                                                                           \
                                                                                  \
      _Pragma("unroll")                                                           \
      for (int n = 0; n < 4; ++n) {                                               \
        const unsigned u0 = pack2bf(s[n][0], s[n][1]);                            \
        const unsigned u1 = pack2bf(s[n][2], s[n][3]);                            \
        *(uint2*)&prow[l15 * PSTR + n * 16 + lg * 4] = make_uint2(u0, u1);        \
      }                                                                           \
      const short8v pf0 = *(const short8v*)&prow[l15 * PSTR + lg * 8];            \
      const short8v pf1 = *(const short8v*)&prow[l15 * PSTR + 32 + lg * 8];       \
                                                                                  \
      _Pragma("unroll")                                                           \
      for (int n = 0; n < 4; ++n) {                                               \
        const int row = n * 16 + l15;                                             \
        const int ch0 = lg ^ (row & 7);                                           \
        const int ch1 = (lg + 4) ^ (row & 7);                                     \
        const short8v vf0 = *(const short8v*)&Vs[buf][row * 64 + ch0 * 8];        \
        const short8v vf1 = *(const short8v*)&Vs[buf][row * 64 + ch1 * 8];        \
        o[n] = __builtin_amdgcn_mfma_f32_16x16x32_bf16(pf0, vf0, o[n], 0, 0, 0);  \
        o[n] = __builtin_amdgcn_mfma_f32_16x16x32_bf16(pf1, vf1, o[n], 0, 0, 0);  \
      }                                                                           \
      asm volatile("" ::: "memory");                                              \
      __builtin_amdgcn_s_barrier();                                               \
      buf ^= 1;                                                                   \
    }                                                                             \
  }

  if (allv) FLASH_LOOP(0)
  else      FLASH_LOOP(1)
#undef FLASH_LOOP
#undef STAGE_KV

#pragma unroll
  for (int jj = 0; jj < 4; ++jj) {
    const float inv = 1.f / __shfl(l_run, lg * 4 + jj, 16);
    const int row = qb * 128 + wave * 16 + lg * 4 + jj;
#pragma unroll
    for (int n = 0; n < 4; ++n)
      ctx[((size_t)(b * TT + row)) * DD + h * 64 + n * 16 + l15] = f2bf(o[n][jj] * inv);
  }
}

// ---------------- fused residual-add + LayerNorm; fp32 residual stream, fp32 g/b
__global__ __launch_bounds__(256) void add_ln(
    const float* __restrict__ xres, const short* __restrict__ add,
    const float* __restrict__ g, const float* __restrict__ bb,
    float* __restrict__ outf, short* __restrict__ outb)
{
  const int row = blockIdx.x, t = threadIdx.x;
  const int lane = t & 63, wave = t >> 6;
  const float4 xv = *(const float4*)(xres + (size_t)row * DD + t * 4);
  float y[4] = { xv.x, xv.y, xv.z, xv.w };
  if (add) {
    const short4v av = *(const short4v*)(add + (size_t)row * DD + t * 4);
#pragma unroll
    for (int i = 0; i < 4; ++i) y[i] += bf2f(av[i]);
  }
  float s = y[0] + y[1] + y[2] + y[3];
  float ss = y[0]*y[0] + y[1]*y[1] + y[2]*y[2] + y[3]*y[3];
#pragma unroll
  for (int off = 32; off >= 1; off >>= 1) {
    s  += __shfl_xor(s, off, 64);
    ss += __shfl_xor(ss, off, 64);
  }
  __shared__ float red[2][4];
  if (lane == 0) { red[0][wave] = s; red[1][wave] = ss; }
  __syncthreads();
  s  = red[0][0] + red[0][1] + red[0][2] + red[0][3];
  ss = red[1][0] + red[1][1] + red[1][2] + red[1][3];
  const float mu = s * (1.f / DD);
  const float var = ss * (1.f / DD) - mu * mu;
  const float rs = rsqrtf(var + 1e-5f);
  const float4 gv = *(const float4*)(g + t * 4);
  const float4 bv = *(const float4*)(bb + t * 4);
  float o[4];
  o[0] = (y[0] - mu) * rs * gv.x + bv.x;
  o[1] = (y[1] - mu) * rs * gv.y + bv.y;
  o[2] = (y[2] - mu) * rs * gv.z + bv.z;
  o[3] = (y[3] - mu) * rs * gv.w + bv.w;
  if (outf) *(float4*)(outf + (size_t)row * DD + t * 4) = make_float4(o[0], o[1], o[2], o[3]);
  if (outb) {
    short4v ov;
#pragma unroll
    for (int i = 0; i < 4; ++i) ov[i] = f2bf(o[i]);
    *(short4v*)(outb + (size_t)row * DD + t * 4) = ov;
  }
}

// ---------------- x (fp32) -> xb (bf16) only; first add_ln reads x directly
__global__ __launch_bounds__(256) void cast_in(
    const float* __restrict__ x, short* __restrict__ xb)
{
  const int i = (blockIdx.x * 256 + threadIdx.x) * 4;
  const float4 v = *(const float4*)(x + i);
  short4v o; o[0] = f2bf(v.x); o[1] = f2bf(v.y); o[2] = f2bf(v.z); o[3] = f2bf(v.w);
  *(short4v*)(xb + i) = o;
}

extern "C" void kernel_launch(void* const* d_in, const int* in_sizes, int n_in,
                              void* d_out, int out_size, void* d_ws, size_t ws_size,
                              hipStream_t stream) {
  const float* x   = (const float*)d_in[0];
  const int* mask  = (const int*)d_in[1];
  const float* Wq  = (const float*)d_in[2];
  const float* bq  = (const float*)d_in[3];
  const float* Wk  = (const float*)d_in[4];
  const float* bk  = (const float*)d_in[5];
  const float* Wv  = (const float*)d_in[6];
  const float* bv  = (const float*)d_in[7];
  const float* Wo  = (const float*)d_in[8];
  const float* bo  = (const float*)d_in[9];
  const float* f1w = (const float*)d_in[10];
  const float* f1b = (const float*)d_in[11];
  const float* f2w = (const float*)d_in[12];
  const float* f2b = (const float*)d_in[13];
  const float* l1g = (const float*)d_in[14];
  const float* l1b = (const float*)d_in[15];
  const float* l2g = (const float*)d_in[16];
  const float* l2b = (const float*)d_in[17];
  const float* lfg = (const float*)d_in[18];
  const float* lfb = (const float*)d_in[19];
  float* out = (float*)d_out;   // reference output dtype is float32

  char* ws = (char*)d_ws;
  const size_t MB = 1u << 20;
  float* xf   = (float*)(ws);              // 0-16  fp32 residual stream
  short* xb   = (short*)(ws + 16 * MB);    // 16-24 bf16 x
  short* qkv  = (short*)(ws + 24 * MB);    // 24-48 fused QKV [4096][3072]
  short* vt_  = (short*)(ws + 48 * MB);    // 48-56 V^T
  short* ctx  = (short*)(ws + 56 * MB);    // 56-64 attention context
  short* tmp  = (short*)(ws + 64 * MB);    // 64-72 attn_out / ff_out
  short* wbuf = (short*)(ws + 72 * MB);    // 72-97.2 layer weights (bf16)
  short* hb   = qkv;                       // FFN hidden 24-56MB (qkv/vt dead)

  cast_in<<<(MM * DD) / (256 * 4), 256, 0, stream>>>(x, xb);

  for (int l = 0; l < LL; ++l) {
    cast_layer<<<WTOT / (256 * 4), 256, 0, stream>>>(
        Wq + (size_t)l * SEG, Wk + (size_t)l * SEG, Wv + (size_t)l * SEG, Wo + (size_t)l * SEG,
        f1w + (size_t)l * DFF * DD, f2w + (size_t)l * DD * DFF, wbuf);
    const short* wqkv_b = wbuf;                       // [3072][1024]
    const short* wo_b   = wbuf + 3 * SEG;
    const short* f1_b   = wbuf + 4 * SEG;
    const short* f2_b   = wbuf + 4 * SEG + DFF * DD;

    gemm256<0,1><<<dim3(3072 / 256, MM / 256), 512, 0, stream>>>(
        xb, wqkv_b, bq + l * DD, bk + l * DD, bv + l * DD, qkv, MM, 3072, DD);
    transpose_v<<<dim3(TT / 64, HH, BB), 256, 0, stream>>>(qkv, vt_);
    flash_attn<<<dim3(TT / 128, HH, BB), 512, 0, stream>>>(qkv, vt_, mask, ctx);
    gemm128<0><<<dim3(DD / 128, MM / 128), 512, 0, stream>>>(ctx, wo_b, bo + l * DD, tmp, MM, DD, DD);
    add_ln<<<MM, 256, 0, stream>>>(l == 0 ? x : xf, tmp, l1g + l * DD, l1b + l * DD, xf, xb);
    gemm256<1,0><<<dim3(DFF / 256, MM / 256), 512, 0, stream>>>(
        xb, f1_b, f1b + l * DFF, nullptr, nullptr, hb, MM, DFF, DD);
    gemm128<0><<<dim3(DD / 128, MM / 128), 512, 0, stream>>>(hb, f2_b, f2b + l * DD, tmp, MM, DD, DFF);
    add_ln<<<MM, 256, 0, stream>>>(xf, tmp, l2g + l * DD, l2b + l * DD, xf, xb);
  }
  add_ln<<<MM, 256, 0, stream>>>(xf, nullptr, lfg, lfb, out, nullptr);
}

// Round 22
// 880.277 us; speedup vs baseline: 1.0408x; 1.0343x over previous
//
#include <hip/hip_runtime.h>
#include <hip/hip_bf16.h>
#include <cstdint>

#define BB 2
#define TT 2048
#define DD 1024
#define HH 16
#define DHH 64
#define DFF 4096
#define LL 4
#define MM (BB*TT)   // 4096 rows
#define NT (TT/64)   // 32 key tiles

typedef __attribute__((ext_vector_type(8))) short short8v;
typedef __attribute__((ext_vector_type(4))) short short4v;
typedef __attribute__((ext_vector_type(4))) float floatx4;

typedef __attribute__((address_space(3))) void lds_void;
typedef const __attribute__((address_space(1))) void glb_void;

__device__ __forceinline__ void gload_lds16(const void* g, void* l) {
  __builtin_amdgcn_global_load_lds((glb_void*)g, (lds_void*)l, 16, 0, 0);
}

__device__ __forceinline__ float bf2f(short s) {
  union { unsigned u; float f; } v; v.u = ((unsigned)(unsigned short)s) << 16; return v.f;
}
__device__ __forceinline__ short f2bf(float f) {
  union { float f; unsigned u; } v; v.f = f;
  unsigned r = (v.u + 0x7fffu + ((v.u >> 16) & 1u)) >> 16;
  return (short)r;
}
__device__ __forceinline__ unsigned pack2bf(float a, float b) {
  __hip_bfloat162 h = __float22bfloat162_rn(make_float2(a, b));
  return *reinterpret_cast<unsigned*>(&h);
}
// raw v_exp_f32 (2^x), ~1ulp; inputs bounded in our uses
__device__ __forceinline__ float fexp2(float x) {
  float r; asm("v_exp_f32 %0, %1" : "=v"(r) : "v"(x)); return r;
}
__device__ __forceinline__ float max3f(float a, float b, float c) {
  float r; asm("v_max3_f32 %0, %1, %2, %3" : "=v"(r) : "v"(a), "v"(b), "v"(c)); return r;
}
// fast GELU (tanh form); |err| < 3e-3, validated R8-R21 (absmax 0.03125)
__device__ __forceinline__ float gelu_fast(float x) {
  const float u = x * x;
  const float w = fmaf(u, -0.10294537f, -2.302203f);
  const float t = fexp2(w * x);
  return x * __builtin_amdgcn_rcpf(1.f + t);
}

#define SCL2 0.18033688011112042f   // 0.125 * log2(e)
__device__ __forceinline__ short8v scale8(short8v v) {
  short8v r;
#pragma unroll
  for (int i = 0; i < 8; ++i) r[i] = f2bf(bf2f(v[i]) * SCL2);
  return r;
}

// ---------------- fp32 -> bf16 cast of one layer's 6 weight matrices into one buffer
#define SEG (DD*DD)              // 1048576
#define WTOT (4*SEG + 2*DFF*DD)  // 12582912
__global__ __launch_bounds__(256) void cast_layer(
    const float* __restrict__ wq, const float* __restrict__ wk,
    const float* __restrict__ wv, const float* __restrict__ wo,
    const float* __restrict__ f1, const float* __restrict__ f2,
    short* __restrict__ dst)
{
  const int i = (blockIdx.x * 256 + threadIdx.x) * 4;
  const float* src; int off;
  if      (i <     SEG) { src = wq; off = i; }
  else if (i < 2 * SEG) { src = wk; off = i - SEG; }
  else if (i < 3 * SEG) { src = wv; off = i - 2 * SEG; }
  else if (i < 4 * SEG) { src = wo; off = i - 3 * SEG; }
  else if (i < 4 * SEG + DFF * DD) { src = f1; off = i - 4 * SEG; }
  else { src = f2; off = i - 4 * SEG - DFF * DD; }
  const float4 v = *(const float4*)(src + off);
  short4v o; o[0] = f2bf(v.x); o[1] = f2bf(v.y); o[2] = f2bf(v.z); o[3] = f2bf(v.w);
  *(short4v*)(dst + i) = o;
}

// ================= 256x256 8-wave 4-phase GEMM (T2+T3+T4+T5) =================
// QKV=1: bias from 3 segment pointers; V-column blocks (bx>=8) also scatter the
// tile to VT[b][h*64+dh][t] (fused V-transpose), packed 4 rows (8B) per store.
template<int GELU, int QKV>
__global__ __launch_bounds__(512, 2) void gemm256(
    const short* __restrict__ A, const short* __restrict__ W,
    const float* __restrict__ b0, const float* __restrict__ b1,
    const float* __restrict__ b2, short* __restrict__ C,
    short* __restrict__ VT,
    int M, int N, int K)
{
  __shared__ __align__(16) short lds[65536];
  const int t = threadIdx.x;
  const int lane = t & 63, wave = t >> 6;
  const int wm = wave >> 2, wn = wave & 3;
  const int l15 = lane & 15, lg = lane >> 4;

  const int nwg = gridDim.x * gridDim.y;
  const int bid0 = blockIdx.y * gridDim.x + blockIdx.x;
  const int q8 = nwg >> 3;
  const int lid = (bid0 & 7) * q8 + (bid0 >> 3);
  const int bx = lid % gridDim.x, by = lid / gridDim.x;

  const size_t abase = (size_t)by * 256 * K;
  const size_t wbase = (size_t)bx * 256 * K;

  floatx4 acc[8][4];
  floatx4 zero = {0.f, 0.f, 0.f, 0.f};
#pragma unroll
  for (int m = 0; m < 8; ++m)
#pragma unroll
    for (int n = 0; n < 4; ++n) acc[m][n] = zero;

#define STG_A(sl_, h_, u_) do {                                                \
    _Pragma("unroll")                                                          \
    for (int j_ = 0; j_ < 2; ++j_) {                                           \
      const int c_ = j_ * 512 + t, r_ = c_ >> 3;                               \
      const int kc_ = (c_ & 7) ^ (r_ & 7);                                     \
      gload_lds16(A + abase + (size_t)((h_) * 128 + r_) * K + (u_) * 64 + kc_ * 8, \
                  &lds[(sl_) * 16384 + (h_) * 8192 + (j_ * 512 + wave * 64) * 8]); \
    } } while (0)
#define STG_B(sl_, h_, u_) do {                                                \
    _Pragma("unroll")                                                          \
    for (int j_ = 0; j_ < 2; ++j_) {                                           \
      const int c_ = j_ * 512 + t, r_ = c_ >> 3;                               \
      const int kc_ = (c_ & 7) ^ (r_ & 7);                                     \
      gload_lds16(W + wbase + (size_t)((h_) * 128 + r_) * K + (u_) * 64 + kc_ * 8, \
                  &lds[32768 + (sl_) * 16384 + (h_) * 8192 + (j_ * 512 + wave * 64) * 8]); \
    } } while (0)

  const int NTK = K >> 6;
  STG_A(0, 0, 0); STG_A(0, 1, 0); STG_B(0, 0, 0); STG_B(0, 1, 0);

  for (int u = 0; u < NTK; ++u) {
    const int sl = u & 1, ns = sl ^ 1;
    const int aoff = sl * 16384 + wm * 8192;
    const int boff = 32768 + sl * 16384 + (wn >> 1) * 8192;
    short8v bfr[4][2];
#pragma unroll
    for (int p = 0; p < 4; ++p) {
      if (p == 0) {
        if (u + 1 < NTK) {
          STG_A(ns, 0, u + 1);
          asm volatile("s_waitcnt vmcnt(2)" ::: "memory");
        } else {
          asm volatile("s_waitcnt vmcnt(0)" ::: "memory");
        }
        __builtin_amdgcn_s_barrier();
#pragma unroll
        for (int n = 0; n < 4; ++n)
#pragma unroll
          for (int kk = 0; kk < 2; ++kk) {
            const int rl = (wn & 1) * 64 + n * 16 + l15;
            bfr[n][kk] = *(const short8v*)&lds[boff + rl * 64 + ((kk * 4 + lg) ^ (rl & 7)) * 8];
          }
      } else if (p == 1) { if (u + 1 < NTK) STG_A(ns, 1, u + 1); }
      else if (p == 2)   { if (u + 1 < NTK) STG_B(ns, 0, u + 1); }
      else               { if (u + 1 < NTK) STG_B(ns, 1, u + 1); }

      short8v af[2][2];
#pragma unroll
      for (int i = 0; i < 2; ++i)
#pragma unroll
        for (int kk = 0; kk < 2; ++kk) {
          const int rl = (2 * p + i) * 16 + l15;
          af[i][kk] = *(const short8v*)&lds[aoff + rl * 64 + ((kk * 4 + lg) ^ (rl & 7)) * 8];
        }
      asm volatile("s_waitcnt lgkmcnt(0)" ::: "memory");
      __builtin_amdgcn_s_setprio(1);
#pragma unroll
      for (int kk = 0; kk < 2; ++kk)
#pragma unroll
        for (int i = 0; i < 2; ++i)
#pragma unroll
          for (int n = 0; n < 4; ++n)
            acc[2 * p + i][n] = __builtin_amdgcn_mfma_f32_16x16x32_bf16(
                af[i][kk], bfr[n][kk], acc[2 * p + i][n], 0, 0, 0);
      __builtin_amdgcn_s_setprio(0);
      __builtin_amdgcn_s_barrier();
    }
  }
#undef STG_A
#undef STG_B

  const float* bp;
  int cbase = bx * 256 + wn * 64;
  if (QKV) {
    const int seg = cbase >> 10;
    bp = (seg == 0) ? b0 : (seg == 1 ? b1 : b2);
    cbase -= seg << 10;
  } else {
    bp = b0;
  }
  float bv[4];
#pragma unroll
  for (int n = 0; n < 4; ++n)
    bv[n] = bp[cbase + n * 16 + l15];
#pragma unroll
  for (int m = 0; m < 8; ++m)
#pragma unroll
    for (int jj = 0; jj < 4; ++jj) {
      const int row = by * 256 + wm * 128 + m * 16 + lg * 4 + jj;
      short* cp = C + (size_t)row * N + bx * 256 + wn * 64 + l15;
#pragma unroll
      for (int n = 0; n < 4; ++n) {
        float v = acc[m][n][jj] + bv[n];
        if (GELU) v = gelu_fast(v);
        cp[n * 16] = f2bf(v);
      }
    }

  // fused V-transpose: V columns (2048..3071) -> VT[(b*1024 + h*64+dh)][t]
  if (QKV && bx >= 8) {
#pragma unroll
    for (int m = 0; m < 8; ++m) {
      const int row0 = by * 256 + wm * 128 + m * 16 + lg * 4;
      const int b_ = row0 >> 11, t_ = row0 & (TT - 1);
#pragma unroll
      for (int n = 0; n < 4; ++n) {
        const int hdh = bx * 256 + wn * 64 + n * 16 + l15 - 2048;
        short4v ov;
#pragma unroll
        for (int jj = 0; jj < 4; ++jj) ov[jj] = f2bf(acc[m][n][jj] + bv[n]);
        *(short4v*)(VT + ((size_t)(b_ * 1024 + hdh)) * TT + t_) = ov;
      }
    }
  }
}

// ====== 128x128 8-wave GEMM, 3-slot LDS, ONE barrier per K-tile (N=1024 shapes) ======
template<int GELU>
__global__ __launch_bounds__(512, 2) void gemm128(
    const short* __restrict__ A, const short* __restrict__ W,
    const float* __restrict__ bias, short* __restrict__ C,
    int M, int N, int K)
{
  __shared__ __align__(16) short lds[49152];  // A: 3 slots @0; B: 3 slots @24576
  const int t = threadIdx.x;
  const int lane = t & 63, wave = t >> 6;
  const int wm = wave >> 2, wn = wave & 3;
  const int l15 = lane & 15, lg = lane >> 4;

  const int nwg = gridDim.x * gridDim.y;
  const int bid0 = blockIdx.y * gridDim.x + blockIdx.x;
  const int q8 = nwg >> 3;
  const int lid = (bid0 & 7) * q8 + (bid0 >> 3);
  const int bx = lid % gridDim.x, by = lid / gridDim.x;

  const size_t abase = (size_t)by * 128 * K;
  const size_t wbase = (size_t)bx * 128 * K;

  floatx4 acc[4][2];
  floatx4 zero = {0.f, 0.f, 0.f, 0.f};
#pragma unroll
  for (int m = 0; m < 4; ++m)
#pragma unroll
    for (int n = 0; n < 2; ++n) acc[m][n] = zero;

#define STG128(sl_, u_) do {                                                   \
    _Pragma("unroll")                                                          \
    for (int j_ = 0; j_ < 2; ++j_) {                                           \
      const int c_ = j_ * 512 + t, r_ = c_ >> 3;                               \
      const int kc_ = (c_ & 7) ^ (r_ & 7);                                     \
      gload_lds16(A + abase + (size_t)r_ * K + (u_) * 64 + kc_ * 8,            \
                  &lds[(sl_) * 8192 + (j_ * 512 + wave * 64) * 8]);            \
      gload_lds16(W + wbase + (size_t)r_ * K + (u_) * 64 + kc_ * 8,            \
                  &lds[24576 + (sl_) * 8192 + (j_ * 512 + wave * 64) * 8]);    \
    } } while (0)

  const int NTK = K >> 6;
  STG128(0, 0);
  STG128(1, 1);

  for (int u = 0; u < NTK; ++u) {
    const int sl = u % 3;
    if (u + 1 < NTK) asm volatile("s_waitcnt vmcnt(4)" ::: "memory");
    else             asm volatile("s_waitcnt vmcnt(0)" ::: "memory");
    __builtin_amdgcn_s_barrier();
    if (u + 2 < NTK) STG128((u + 2) % 3, u + 2);

    short8v bfr[2][2], af[4][2];
#pragma unroll
    for (int n = 0; n < 2; ++n)
#pragma unroll
      for (int kk = 0; kk < 2; ++kk) {
        const int rl = wn * 32 + n * 16 + l15;
        bfr[n][kk] = *(const short8v*)&lds[24576 + sl * 8192 + rl * 64 + ((kk * 4 + lg) ^ (rl & 7)) * 8];
      }
#pragma unroll
    for (int m = 0; m < 4; ++m)
#pragma unroll
      for (int kk = 0; kk < 2; ++kk) {
        const int rl = wm * 32 + ((m & 1) * 16) + l15 + (m >> 1) * 64;
        af[m][kk] = *(const short8v*)&lds[sl * 8192 + rl * 64 + ((kk * 4 + lg) ^ (rl & 7)) * 8];
      }
    asm volatile("s_waitcnt lgkmcnt(0)" ::: "memory");
    __builtin_amdgcn_s_setprio(1);
#pragma unroll
    for (int kk = 0; kk < 2; ++kk)
#pragma unroll
      for (int m = 0; m < 4; ++m)
#pragma unroll
        for (int n = 0; n < 2; ++n)
          acc[m][n] = __builtin_amdgcn_mfma_f32_16x16x32_bf16(af[m][kk], bfr[n][kk], acc[m][n], 0, 0, 0);
    __builtin_amdgcn_s_setprio(0);
  }
#undef STG128

  float bv[2];
#pragma unroll
  for (int n = 0; n < 2; ++n)
    bv[n] = bias[bx * 128 + wn * 32 + n * 16 + l15];
#pragma unroll
  for (int m = 0; m < 4; ++m)
#pragma unroll
    for (int jj = 0; jj < 4; ++jj) {
      const int row = by * 128 + wm * 32 + (m & 1) * 16 + (m >> 1) * 64 + lg * 4 + jj;
      short* cp = C + (size_t)row * N + bx * 128 + wn * 32 + l15;
#pragma unroll
      for (int n = 0; n < 2; ++n) {
        float v = acc[m][n][jj] + bv[n];
        if (GELU) v = gelu_fast(v);
        cp[n * 16] = f2bf(v);
      }
    }
}

// ---------------- flash attention (R19 champion): 1 block = 128 q-rows; 8 waves x
// 16 q-rows. Swapped QK^T, pre-scaled Q, raw v_exp, max3 tree, 2-slot KV dbuf +
// counted vmcnt, defer-max, XCD swizzle, block-uniform mask fast path.
#define PSTR 72
__global__ __launch_bounds__(512, 4) void flash_attn(
    const short* __restrict__ qkv, const short* __restrict__ vt,
    const int* __restrict__ mask, short* __restrict__ ctx)
{
  const int t = threadIdx.x;
  const int lane = t & 63, wave = t >> 6;
  const int l15 = lane & 15, lg = lane >> 4;

  const int bid0 = blockIdx.x + gridDim.x * (blockIdx.y + gridDim.y * blockIdx.z);
  const int lid = (bid0 & 7) * 64 + (bid0 >> 3);
  const int qb = lid & 15, h = (lid >> 4) & 15, b = lid >> 8;

  __shared__ __align__(16) short Ks[2][64 * 64];
  __shared__ __align__(16) short Vs[2][64 * 64];
  __shared__ __align__(16) short p_lds[8][16 * PSTR];
  __shared__ int allv_lds;
  short* prow = p_lds[wave];

  // block-uniform mask check: 512 threads x int4 cover all 2048 keys of batch b
  if (t == 0) allv_lds = 1;
  __syncthreads();
  {
    const int4 mv = *(const int4*)&mask[b * TT + t * 4];
    if (!(mv.x && mv.y && mv.z && mv.w)) allv_lds = 0;   // benign race: all writers store 0
  }
  __syncthreads();
  const bool allv = (allv_lds != 0);

  const short* qp = qkv + ((size_t)(b * TT + qb * 128 + wave * 16 + l15)) * 3072 + h * 64;
  const short8v qf0 = scale8(*(const short8v*)(qp + lg * 8));
  const short8v qf1 = scale8(*(const short8v*)(qp + 32 + lg * 8));

  const short* kbase = qkv + (size_t)b * TT * 3072 + 1024 + h * 64;
  const short* vtb   = vt + ((size_t)(b * HH + h)) * 64 * TT;

  const int srow = lane >> 3;
  const int scol = (lane & 7) ^ (srow & 7);

  float m_run = -3e30f, l_run = 0.f;
  floatx4 zero = {0.f, 0.f, 0.f, 0.f};
  floatx4 o[4];
#pragma unroll
  for (int n = 0; n < 4; ++n) o[n] = zero;

#define STAGE_KV(bufi, kb_) do {                                             \
    const int r_ = wave * 8 + srow;                                          \
    gload_lds16(kbase + (size_t)((kb_) * 64 + r_) * 3072 + scol * 8,         \
                &Ks[bufi][wave * 512]);                                      \
    gload_lds16(vtb + (size_t)r_ * TT + (kb_) * 64 + scol * 8,               \
                &Vs[bufi][wave * 512]);                                      \
  } while (0)

#define FLASH_LOOP(MASKED)                                                        \
  {                                                                               \
    STAGE_KV(0, 0);                                                               \
    int buf = 0;                                                                  \
    for (int kb = 0; kb < NT; ++kb) {                                             \
      if (kb + 1 < NT) {                                                          \
        STAGE_KV(buf ^ 1, kb + 1);                                                \
        asm volatile("s_waitcnt vmcnt(2)" ::: "memory");                          \
      } else {                                                                    \
        asm volatile("s_waitcnt vmcnt(0)" ::: "memory");                          \
      }                                                                           \
      __builtin_amdgcn_s_barrier();                                               \
                                                                                  \
      float cm[4][4];                                                             \
      if (MASKED) {                                                               \
        _Pragma("unroll")                                                         \
        for (int n = 0; n < 4; ++n) {                                             \
          const int4 mv = *(const int4*)&mask[b * TT + kb * 64 + n * 16 + lg * 4];\
          cm[n][0] = mv.x ? 0.f : -1.5e30f; cm[n][1] = mv.y ? 0.f : -1.5e30f;     \
          cm[n][2] = mv.z ? 0.f : -1.5e30f; cm[n][3] = mv.w ? 0.f : -1.5e30f;     \
        }                                                                         \
      }                                                                           \
                                                                                  \
      floatx4 s[4];                                                               \
      _Pragma("unroll")                                                           \
      for (int n = 0; n < 4; ++n) {                                               \
        const int row = n * 16 + l15;                                             \
        const int ch0 = lg ^ (row & 7);                                           \
        const int ch1 = (lg + 4) ^ (row & 7);                                     \
        const short8v kf0 = *(const short8v*)&Ks[buf][row * 64 + ch0 * 8];        \
        const short8v kf1 = *(const short8v*)&Ks[buf][row * 64 + ch1 * 8];        \
        floatx4 a = zero;                                                         \
        a = __builtin_amdgcn_mfma_f32_16x16x32_bf16(kf0, qf0, a, 0, 0, 0);        \
        a = __builtin_amdgcn_mfma_f32_16x16x32_bf16(kf1, qf1, a, 0, 0, 0);        \
        s[n] = a;                                                                 \
      }                                                                           \
      if (MASKED) {                                                               \
        _Pragma("unroll")                                                         \
        for (int n = 0; n < 4; ++n)                                               \
          _Pragma("unroll")                                                       \
          for (int jj = 0; jj < 4; ++jj) s[n][jj] += cm[n][jj];                   \
      }                                                                           \
                                                                                  \
      const float t0 = max3f(s[0][0], s[0][1], s[0][2]);                          \
      const float t1 = max3f(s[0][3], s[1][0], s[1][1]);                          \
      const float t2 = max3f(s[1][2], s[1][3], s[2][0]);                          \
      const float t3 = max3f(s[2][1], s[2][2], s[2][3]);                          \
      const float t4 = max3f(s[3][0], s[3][1], s[3][2]);                          \
      float mx = fmaxf(max3f(t0, t1, t2), max3f(t3, t4, s[3][3]));                \
      mx = fmaxf(mx, __shfl_xor(mx, 16, 64));                                     \
      mx = fmaxf(mx, __shfl_xor(mx, 32, 64));                                     \
                                                                                  \
      const bool defer = __all(mx - m_run <= 11.5f);                              \
      const float mnew = defer ? m_run : fmaxf(m_run, mx);                        \
      float ps[4];                                                                \
      _Pragma("unroll")                                                           \
      for (int n = 0; n < 4; ++n) {                                               \
        s[n][0] = fexp2(s[n][0] - mnew);                                          \
        s[n][1] = fexp2(s[n][1] - mnew);                                          \
        s[n][2] = fexp2(s[n][2] - mnew);                                          \
        s[n][3] = fexp2(s[n][3] - mnew);                                          \
        ps[n] = (s[n][0] + s[n][1]) + (s[n][2] + s[n][3]);                        \
      }                                                                           \
      float sum = (ps[0] + ps[1]) + (ps[2] + ps[3]);                              \
      sum += __shfl_xor(sum, 16, 64);                                             \
      sum += __shfl_xor(sum, 32, 64);                                             \
      if (defer) {                                                                \
        l_run += sum;                                                             \
      } else {                                                                    \
        const float al = fexp2(m_run - mnew);                                     \
        l_run = l_run * al + sum;                                                 \
        m_run = mnew;                                                             \
        float alo[4];                                                             \
        _Pragma("unroll")                                                         \
        for (int jj = 0; jj < 4; ++jj) alo[jj] = __shfl(al, lg * 4 + jj, 16);     \
        _Pragma("unroll")                                                         \
        for (int n = 0; n < 4; ++n)                                               \
          _Pragma("unroll")                                                       \
          for (int jj = 0; jj < 4; ++jj) o[n][jj] *= alo[jj];                     \
      }                                                                           \
                                                                                  \
      _Pragma("unroll")                                                           \
      for (int n = 0; n < 4; ++n) {                                               \
        const unsigned u0 = pack2bf(s[n][0], s[n][1]);                            \
        const unsigned u1 = pack2bf(s[n][2], s[n][3]);                            \
        *(uint2*)&prow[l15 * PSTR + n * 16 + lg * 4] = make_uint2(u0, u1);        \
      }                                                                           \
      const short8v pf0 = *(const short8v*)&prow[l15 * PSTR + lg * 8];            \
      const short8v pf1 = *(const short8v*)&prow[l15 * PSTR + 32 + lg * 8];       \
                                                                                  \
      _Pragma("unroll")                                                           \
      for (int n = 0; n < 4; ++n) {                                               \
        const int row = n * 16 + l15;                                             \
        const int ch0 = lg ^ (row & 7);                                           \
        const int ch1 = (lg + 4) ^ (row & 7);                                     \
        const short8v vf0 = *(const short8v*)&Vs[buf][row * 64 + ch0 * 8];        \
        const short8v vf1 = *(const short8v*)&Vs[buf][row * 64 + ch1 * 8];        \
        o[n] = __builtin_amdgcn_mfma_f32_16x16x32_bf16(pf0, vf0, o[n], 0, 0, 0);  \
        o[n] = __builtin_amdgcn_mfma_f32_16x16x32_bf16(pf1, vf1, o[n], 0, 0, 0);  \
      }                                                                           \
      asm volatile("" ::: "memory");                                              \
      __builtin_amdgcn_s_barrier();                                               \
      buf ^= 1;                                                                   \
    }                                                                             \
  }

  if (allv) FLASH_LOOP(0)
  else      FLASH_LOOP(1)
#undef FLASH_LOOP
#undef STAGE_KV

#pragma unroll
  for (int jj = 0; jj < 4; ++jj) {
    const float inv = 1.f / __shfl(l_run, lg * 4 + jj, 16);
    const int row = qb * 128 + wave * 16 + lg * 4 + jj;
#pragma unroll
    for (int n = 0; n < 4; ++n)
      ctx[((size_t)(b * TT + row)) * DD + h * 64 + n * 16 + l15] = f2bf(o[n][jj] * inv);
  }
}

// ---------------- fused residual-add + LayerNorm; bf16 residual stream
// XF32: residual input is fp32 (first layer reads x); OUTF: write fp32 (final LN)
template<int XF32, int OUTF>
__global__ __launch_bounds__(256) void add_ln(
    const float* __restrict__ xrf, const short* __restrict__ xrb,
    const short* __restrict__ add,
    const float* __restrict__ g, const float* __restrict__ bb,
    float* __restrict__ outf, short* __restrict__ outb)
{
  const int row = blockIdx.x, t = threadIdx.x;
  const int lane = t & 63, wave = t >> 6;
  float y[4];
  if (XF32) {
    const float4 xv = *(const float4*)(xrf + (size_t)row * DD + t * 4);
    y[0] = xv.x; y[1] = xv.y; y[2] = xv.z; y[3] = xv.w;
  } else {
    const short4v xv = *(const short4v*)(xrb + (size_t)row * DD + t * 4);
#pragma unroll
    for (int i = 0; i < 4; ++i) y[i] = bf2f(xv[i]);
  }
  if (add) {
    const short4v av = *(const short4v*)(add + (size_t)row * DD + t * 4);
#pragma unroll
    for (int i = 0; i < 4; ++i) y[i] += bf2f(av[i]);
  }
  float s = y[0] + y[1] + y[2] + y[3];
  float ss = y[0]*y[0] + y[1]*y[1] + y[2]*y[2] + y[3]*y[3];
#pragma unroll
  for (int off = 32; off >= 1; off >>= 1) {
    s  += __shfl_xor(s, off, 64);
    ss += __shfl_xor(ss, off, 64);
  }
  __shared__ float red[2][4];
  if (lane == 0) { red[0][wave] = s; red[1][wave] = ss; }
  __syncthreads();
  s  = red[0][0] + red[0][1] + red[0][2] + red[0][3];
  ss = red[1][0] + red[1][1] + red[1][2] + red[1][3];
  const float mu = s * (1.f / DD);
  const float var = ss * (1.f / DD) - mu * mu;
  const float rs = rsqrtf(var + 1e-5f);
  const float4 gv = *(const float4*)(g + t * 4);
  const float4 bv = *(const float4*)(bb + t * 4);
  float o[4];
  o[0] = (y[0] - mu) * rs * gv.x + bv.x;
  o[1] = (y[1] - mu) * rs * gv.y + bv.y;
  o[2] = (y[2] - mu) * rs * gv.z + bv.z;
  o[3] = (y[3] - mu) * rs * gv.w + bv.w;
  if (OUTF) {
    *(float4*)(outf + (size_t)row * DD + t * 4) = make_float4(o[0], o[1], o[2], o[3]);
  } else {
    short4v ov;
#pragma unroll
    for (int i = 0; i < 4; ++i) ov[i] = f2bf(o[i]);
    *(short4v*)(outb + (size_t)row * DD + t * 4) = ov;
  }
}

// ---------------- x (fp32) -> xr (bf16); first add_ln reads x (fp32) directly
__global__ __launch_bounds__(256) void cast_in(
    const float* __restrict__ x, short* __restrict__ xr)
{
  const int i = (blockIdx.x * 256 + threadIdx.x) * 4;
  const float4 v = *(const float4*)(x + i);
  short4v o; o[0] = f2bf(v.x); o[1] = f2bf(v.y); o[2] = f2bf(v.z); o[3] = f2bf(v.w);
  *(short4v*)(xr + i) = o;
}

extern "C" void kernel_launch(void* const* d_in, const int* in_sizes, int n_in,
                              void* d_out, int out_size, void* d_ws, size_t ws_size,
                              hipStream_t stream) {
  const float* x   = (const float*)d_in[0];
  const int* mask  = (const int*)d_in[1];
  const float* Wq  = (const float*)d_in[2];
  const float* bq  = (const float*)d_in[3];
  const float* Wk  = (const float*)d_in[4];
  const float* bk  = (const float*)d_in[5];
  const float* Wv  = (const float*)d_in[6];
  const float* bv  = (const float*)d_in[7];
  const float* Wo  = (const float*)d_in[8];
  const float* bo  = (const float*)d_in[9];
  const float* f1w = (const float*)d_in[10];
  const float* f1b = (const float*)d_in[11];
  const float* f2w = (const float*)d_in[12];
  const float* f2b = (const float*)d_in[13];
  const float* l1g = (const float*)d_in[14];
  const float* l1b = (const float*)d_in[15];
  const float* l2g = (const float*)d_in[16];
  const float* l2b = (const float*)d_in[17];
  const float* lfg = (const float*)d_in[18];
  const float* lfb = (const float*)d_in[19];
  float* out = (float*)d_out;   // reference output dtype is float32

  char* ws = (char*)d_ws;
  const size_t MB = 1u << 20;
  short* xr   = (short*)(ws);              // 0-8   bf16 residual stream (also GEMM A)
  short* qkv  = (short*)(ws + 8 * MB);     // 8-32  fused QKV [4096][3072]
  short* vt_  = (short*)(ws + 32 * MB);    // 32-40 V^T (written by gemm256 epilogue)
  short* ctx  = (short*)(ws + 40 * MB);    // 40-48 attention context
  short* tmp  = (short*)(ws + 48 * MB);    // 48-56 attn_out / ff_out
  short* wbuf = (short*)(ws + 56 * MB);    // 56-81.2 layer weights (bf16)
  short* hb   = qkv;                       // FFN hidden 8-40MB (qkv+vt dead after flash)

  cast_in<<<(MM * DD) / (256 * 4), 256, 0, stream>>>(x, xr);

  for (int l = 0; l < LL; ++l) {
    cast_layer<<<WTOT / (256 * 4), 256, 0, stream>>>(
        Wq + (size_t)l * SEG, Wk + (size_t)l * SEG, Wv + (size_t)l * SEG, Wo + (size_t)l * SEG,
        f1w + (size_t)l * DFF * DD, f2w + (size_t)l * DD * DFF, wbuf);
    const short* wqkv_b = wbuf;                       // [3072][1024]
    const short* wo_b   = wbuf + 3 * SEG;
    const short* f1_b   = wbuf + 4 * SEG;
    const short* f2_b   = wbuf + 4 * SEG + DFF * DD;

    gemm256<0,1><<<dim3(3072 / 256, MM / 256), 512, 0, stream>>>(
        xr, wqkv_b, bq + l * DD, bk + l * DD, bv + l * DD, qkv, vt_, MM, 3072, DD);
    flash_attn<<<dim3(TT / 128, HH, BB), 512, 0, stream>>>(qkv, vt_, mask, ctx);
    gemm128<0><<<dim3(DD / 128, MM / 128), 512, 0, stream>>>(ctx, wo_b, bo + l * DD, tmp, MM, DD, DD);
    if (l == 0)
      add_ln<1,0><<<MM, 256, 0, stream>>>(x, nullptr, tmp, l1g, l1b, nullptr, xr);
    else
      add_ln<0,0><<<MM, 256, 0, stream>>>(nullptr, xr, tmp, l1g + l * DD, l1b + l * DD, nullptr, xr);
    gemm256<1,0><<<dim3(DFF / 256, MM / 256), 512, 0, stream>>>(
        xr, f1_b, f1b + l * DFF, nullptr, nullptr, hb, nullptr, MM, DFF, DD);
    gemm128<0><<<dim3(DD / 128, MM / 128), 512, 0, stream>>>(hb, f2_b, f2b + l * DD, tmp, MM, DD, DFF);
    add_ln<0,0><<<MM, 256, 0, stream>>>(nullptr, xr, tmp, l2g + l * DD, l2b + l * DD, nullptr, xr);
  }
  add_ln<0,1><<<MM, 256, 0, stream>>>(nullptr, xr, nullptr, lfg, lfb, out, nullptr);
}

// Round 23
// 866.284 us; speedup vs baseline: 1.0576x; 1.0162x over previous
//
#include <hip/hip_runtime.h>
#include <hip/hip_bf16.h>
#include <cstdint>

#define BB 2
#define TT 2048
#define DD 1024
#define HH 16
#define DHH 64
#define DFF 4096
#define LL 4
#define MM (BB*TT)   // 4096 rows
#define NT (TT/64)   // 32 key tiles

typedef __attribute__((ext_vector_type(8))) short short8v;
typedef __attribute__((ext_vector_type(4))) short short4v;
typedef __attribute__((ext_vector_type(4))) float floatx4;

typedef __attribute__((address_space(3))) void lds_void;
typedef const __attribute__((address_space(1))) void glb_void;

__device__ __forceinline__ void gload_lds16(const void* g, void* l) {
  __builtin_amdgcn_global_load_lds((glb_void*)g, (lds_void*)l, 16, 0, 0);
}

__device__ __forceinline__ float bf2f(short s) {
  union { unsigned u; float f; } v; v.u = ((unsigned)(unsigned short)s) << 16; return v.f;
}
__device__ __forceinline__ short f2bf(float f) {
  union { float f; unsigned u; } v; v.f = f;
  unsigned r = (v.u + 0x7fffu + ((v.u >> 16) & 1u)) >> 16;
  return (short)r;
}
__device__ __forceinline__ unsigned pack2bf(float a, float b) {
  __hip_bfloat162 h = __float22bfloat162_rn(make_float2(a, b));
  return *reinterpret_cast<unsigned*>(&h);
}
// raw v_exp_f32 (2^x), ~1ulp; inputs bounded in our uses
__device__ __forceinline__ float fexp2(float x) {
  float r; asm("v_exp_f32 %0, %1" : "=v"(r) : "v"(x)); return r;
}
__device__ __forceinline__ float max3f(float a, float b, float c) {
  float r; asm("v_max3_f32 %0, %1, %2, %3" : "=v"(r) : "v"(a), "v"(b), "v"(c)); return r;
}
// fast GELU (tanh form); |err| < 3e-3, validated R8-R22 (absmax <= 0.047)
__device__ __forceinline__ float gelu_fast(float x) {
  const float u = x * x;
  const float w = fmaf(u, -0.10294537f, -2.302203f);
  const float t = fexp2(w * x);
  return x * __builtin_amdgcn_rcpf(1.f + t);
}

#define SCL2 0.18033688011112042f   // 0.125 * log2(e)
__device__ __forceinline__ short8v scale8(short8v v) {
  short8v r;
#pragma unroll
  for (int i = 0; i < 8; ++i) r[i] = f2bf(bf2f(v[i]) * SCL2);
  return r;
}

// ---------------- fp32 -> bf16 cast of one layer's 6 weight matrices into one buffer
#define SEG (DD*DD)              // 1048576
#define WTOT (4*SEG + 2*DFF*DD)  // 12582912
__global__ __launch_bounds__(256) void cast_layer(
    const float* __restrict__ wq, const float* __restrict__ wk,
    const float* __restrict__ wv, const float* __restrict__ wo,
    const float* __restrict__ f1, const float* __restrict__ f2,
    short* __restrict__ dst)
{
  const int i = (blockIdx.x * 256 + threadIdx.x) * 4;
  const float* src; int off;
  if      (i <     SEG) { src = wq; off = i; }
  else if (i < 2 * SEG) { src = wk; off = i - SEG; }
  else if (i < 3 * SEG) { src = wv; off = i - 2 * SEG; }
  else if (i < 4 * SEG) { src = wo; off = i - 3 * SEG; }
  else if (i < 4 * SEG + DFF * DD) { src = f1; off = i - 4 * SEG; }
  else { src = f2; off = i - 4 * SEG - DFF * DD; }
  const float4 v = *(const float4*)(src + off);
  short4v o; o[0] = f2bf(v.x); o[1] = f2bf(v.y); o[2] = f2bf(v.z); o[3] = f2bf(v.w);
  *(short4v*)(dst + i) = o;
}

// ================= 256x256 8-wave 4-phase GEMM (T2+T3+T4+T5) =================
// QKV=1: bias from 3 segment pointers; V-column blocks (bx>=8) scatter the tile
// to VT[b][h*64+dh][t] (fused V-transpose) and SKIP the dead row-major C-store.
template<int GELU, int QKV>
__global__ __launch_bounds__(512, 2) void gemm256(
    const short* __restrict__ A, const short* __restrict__ W,
    const float* __restrict__ b0, const float* __restrict__ b1,
    const float* __restrict__ b2, short* __restrict__ C,
    short* __restrict__ VT,
    int M, int N, int K)
{
  __shared__ __align__(16) short lds[65536];
  const int t = threadIdx.x;
  const int lane = t & 63, wave = t >> 6;
  const int wm = wave >> 2, wn = wave & 3;
  const int l15 = lane & 15, lg = lane >> 4;

  const int nwg = gridDim.x * gridDim.y;
  const int bid0 = blockIdx.y * gridDim.x + blockIdx.x;
  const int q8 = nwg >> 3;
  const int lid = (bid0 & 7) * q8 + (bid0 >> 3);
  const int bx = lid % gridDim.x, by = lid / gridDim.x;

  const size_t abase = (size_t)by * 256 * K;
  const size_t wbase = (size_t)bx * 256 * K;

  floatx4 acc[8][4];
  floatx4 zero = {0.f, 0.f, 0.f, 0.f};
#pragma unroll
  for (int m = 0; m < 8; ++m)
#pragma unroll
    for (int n = 0; n < 4; ++n) acc[m][n] = zero;

#define STG_A(sl_, h_, u_) do {                                                \
    _Pragma("unroll")                                                          \
    for (int j_ = 0; j_ < 2; ++j_) {                                           \
      const int c_ = j_ * 512 + t, r_ = c_ >> 3;                               \
      const int kc_ = (c_ & 7) ^ (r_ & 7);                                     \
      gload_lds16(A + abase + (size_t)((h_) * 128 + r_) * K + (u_) * 64 + kc_ * 8, \
                  &lds[(sl_) * 16384 + (h_) * 8192 + (j_ * 512 + wave * 64) * 8]); \
    } } while (0)
#define STG_B(sl_, h_, u_) do {                                                \
    _Pragma("unroll")                                                          \
    for (int j_ = 0; j_ < 2; ++j_) {                                           \
      const int c_ = j_ * 512 + t, r_ = c_ >> 3;                               \
      const int kc_ = (c_ & 7) ^ (r_ & 7);                                     \
      gload_lds16(W + wbase + (size_t)((h_) * 128 + r_) * K + (u_) * 64 + kc_ * 8, \
                  &lds[32768 + (sl_) * 16384 + (h_) * 8192 + (j_ * 512 + wave * 64) * 8]); \
    } } while (0)

  const int NTK = K >> 6;
  STG_A(0, 0, 0); STG_A(0, 1, 0); STG_B(0, 0, 0); STG_B(0, 1, 0);

  for (int u = 0; u < NTK; ++u) {
    const int sl = u & 1, ns = sl ^ 1;
    const int aoff = sl * 16384 + wm * 8192;
    const int boff = 32768 + sl * 16384 + (wn >> 1) * 8192;
    short8v bfr[4][2];
#pragma unroll
    for (int p = 0; p < 4; ++p) {
      if (p == 0) {
        if (u + 1 < NTK) {
          STG_A(ns, 0, u + 1);
          asm volatile("s_waitcnt vmcnt(2)" ::: "memory");
        } else {
          asm volatile("s_waitcnt vmcnt(0)" ::: "memory");
        }
        __builtin_amdgcn_s_barrier();
#pragma unroll
        for (int n = 0; n < 4; ++n)
#pragma unroll
          for (int kk = 0; kk < 2; ++kk) {
            const int rl = (wn & 1) * 64 + n * 16 + l15;
            bfr[n][kk] = *(const short8v*)&lds[boff + rl * 64 + ((kk * 4 + lg) ^ (rl & 7)) * 8];
          }
      } else if (p == 1) { if (u + 1 < NTK) STG_A(ns, 1, u + 1); }
      else if (p == 2)   { if (u + 1 < NTK) STG_B(ns, 0, u + 1); }
      else               { if (u + 1 < NTK) STG_B(ns, 1, u + 1); }

      short8v af[2][2];
#pragma unroll
      for (int i = 0; i < 2; ++i)
#pragma unroll
        for (int kk = 0; kk < 2; ++kk) {
          const int rl = (2 * p + i) * 16 + l15;
          af[i][kk] = *(const short8v*)&lds[aoff + rl * 64 + ((kk * 4 + lg) ^ (rl & 7)) * 8];
        }
      asm volatile("s_waitcnt lgkmcnt(0)" ::: "memory");
      __builtin_amdgcn_s_setprio(1);
#pragma unroll
      for (int kk = 0; kk < 2; ++kk)
#pragma unroll
        for (int i = 0; i < 2; ++i)
#pragma unroll
          for (int n = 0; n < 4; ++n)
            acc[2 * p + i][n] = __builtin_amdgcn_mfma_f32_16x16x32_bf16(
                af[i][kk], bfr[n][kk], acc[2 * p + i][n], 0, 0, 0);
      __builtin_amdgcn_s_setprio(0);
      __builtin_amdgcn_s_barrier();
    }
  }
#undef STG_A
#undef STG_B

  const float* bp;
  int cbase = bx * 256 + wn * 64;
  if (QKV) {
    const int seg = cbase >> 10;
    bp = (seg == 0) ? b0 : (seg == 1 ? b1 : b2);
    cbase -= seg << 10;
  } else {
    bp = b0;
  }
  float bv[4];
#pragma unroll
  for (int n = 0; n < 4; ++n)
    bv[n] = bp[cbase + n * 16 + l15];

  // row-major C-store: skipped for V columns (dead — flash reads V only via VT)
  if (!QKV || bx < 8) {
#pragma unroll
    for (int m = 0; m < 8; ++m)
#pragma unroll
      for (int jj = 0; jj < 4; ++jj) {
        const int row = by * 256 + wm * 128 + m * 16 + lg * 4 + jj;
        short* cp = C + (size_t)row * N + bx * 256 + wn * 64 + l15;
#pragma unroll
        for (int n = 0; n < 4; ++n) {
          float v = acc[m][n][jj] + bv[n];
          if (GELU) v = gelu_fast(v);
          cp[n * 16] = f2bf(v);
        }
      }
  }

  // fused V-transpose: V columns (2048..3071) -> VT[(b*1024 + h*64+dh)][t]
  if (QKV && bx >= 8) {
#pragma unroll
    for (int m = 0; m < 8; ++m) {
      const int row0 = by * 256 + wm * 128 + m * 16 + lg * 4;
      const int b_ = row0 >> 11, t_ = row0 & (TT - 1);
#pragma unroll
      for (int n = 0; n < 4; ++n) {
        const int hdh = bx * 256 + wn * 64 + n * 16 + l15 - 2048;
        short4v ov;
#pragma unroll
        for (int jj = 0; jj < 4; ++jj) ov[jj] = f2bf(acc[m][n][jj] + bv[n]);
        *(short4v*)(VT + ((size_t)(b_ * 1024 + hdh)) * TT + t_) = ov;
      }
    }
  }
}

// ====== 128x128 8-wave GEMM, 3-slot LDS, ONE barrier per K-tile (N=1024 shapes) ======
template<int GELU>
__global__ __launch_bounds__(512, 2) void gemm128(
    const short* __restrict__ A, const short* __restrict__ W,
    const float* __restrict__ bias, short* __restrict__ C,
    int M, int N, int K)
{
  __shared__ __align__(16) short lds[49152];  // A: 3 slots @0; B: 3 slots @24576
  const int t = threadIdx.x;
  const int lane = t & 63, wave = t >> 6;
  const int wm = wave >> 2, wn = wave & 3;
  const int l15 = lane & 15, lg = lane >> 4;

  const int nwg = gridDim.x * gridDim.y;
  const int bid0 = blockIdx.y * gridDim.x + blockIdx.x;
  const int q8 = nwg >> 3;
  const int lid = (bid0 & 7) * q8 + (bid0 >> 3);
  const int bx = lid % gridDim.x, by = lid / gridDim.x;

  const size_t abase = (size_t)by * 128 * K;
  const size_t wbase = (size_t)bx * 128 * K;

  floatx4 acc[4][2];
  floatx4 zero = {0.f, 0.f, 0.f, 0.f};
#pragma unroll
  for (int m = 0; m < 4; ++m)
#pragma unroll
    for (int n = 0; n < 2; ++n) acc[m][n] = zero;

#define STG128(sl_, u_) do {                                                   \
    _Pragma("unroll")                                                          \
    for (int j_ = 0; j_ < 2; ++j_) {                                           \
      const int c_ = j_ * 512 + t, r_ = c_ >> 3;                               \
      const int kc_ = (c_ & 7) ^ (r_ & 7);                                     \
      gload_lds16(A + abase + (size_t)r_ * K + (u_) * 64 + kc_ * 8,            \
                  &lds[(sl_) * 8192 + (j_ * 512 + wave * 64) * 8]);            \
      gload_lds16(W + wbase + (size_t)r_ * K + (u_) * 64 + kc_ * 8,            \
                  &lds[24576 + (sl_) * 8192 + (j_ * 512 + wave * 64) * 8]);    \
    } } while (0)

  const int NTK = K >> 6;
  STG128(0, 0);
  STG128(1, 1);

  for (int u = 0; u < NTK; ++u) {
    const int sl = u % 3;
    if (u + 1 < NTK) asm volatile("s_waitcnt vmcnt(4)" ::: "memory");
    else             asm volatile("s_waitcnt vmcnt(0)" ::: "memory");
    __builtin_amdgcn_s_barrier();
    if (u + 2 < NTK) STG128((u + 2) % 3, u + 2);

    short8v bfr[2][2], af[4][2];
#pragma unroll
    for (int n = 0; n < 2; ++n)
#pragma unroll
      for (int kk = 0; kk < 2; ++kk) {
        const int rl = wn * 32 + n * 16 + l15;
        bfr[n][kk] = *(const short8v*)&lds[24576 + sl * 8192 + rl * 64 + ((kk * 4 + lg) ^ (rl & 7)) * 8];
      }
#pragma unroll
    for (int m = 0; m < 4; ++m)
#pragma unroll
      for (int kk = 0; kk < 2; ++kk) {
        const int rl = wm * 32 + ((m & 1) * 16) + l15 + (m >> 1) * 64;
        af[m][kk] = *(const short8v*)&lds[sl * 8192 + rl * 64 + ((kk * 4 + lg) ^ (rl & 7)) * 8];
      }
    asm volatile("s_waitcnt lgkmcnt(0)" ::: "memory");
    __builtin_amdgcn_s_setprio(1);
#pragma unroll
    for (int kk = 0; kk < 2; ++kk)
#pragma unroll
      for (int m = 0; m < 4; ++m)
#pragma unroll
        for (int n = 0; n < 2; ++n)
          acc[m][n] = __builtin_amdgcn_mfma_f32_16x16x32_bf16(af[m][kk], bfr[n][kk], acc[m][n], 0, 0, 0);
    __builtin_amdgcn_s_setprio(0);
  }
#undef STG128

  float bv[2];
#pragma unroll
  for (int n = 0; n < 2; ++n)
    bv[n] = bias[bx * 128 + wn * 32 + n * 16 + l15];
#pragma unroll
  for (int m = 0; m < 4; ++m)
#pragma unroll
    for (int jj = 0; jj < 4; ++jj) {
      const int row = by * 128 + wm * 32 + (m & 1) * 16 + (m >> 1) * 64 + lg * 4 + jj;
      short* cp = C + (size_t)row * N + bx * 128 + wn * 32 + l15;
#pragma unroll
      for (int n = 0; n < 2; ++n) {
        float v = acc[m][n][jj] + bv[n];
        if (GELU) v = gelu_fast(v);
        cp[n * 16] = f2bf(v);
      }
    }
}

// ---------------- flash attention (R19 champion): 1 block = 128 q-rows; 8 waves x
// 16 q-rows. Swapped QK^T, pre-scaled Q, raw v_exp, max3 tree, 2-slot KV dbuf +
// counted vmcnt, defer-max, XCD swizzle, block-uniform mask fast path.
#define PSTR 72
__global__ __launch_bounds__(512, 4) void flash_attn(
    const short* __restrict__ qkv, const short* __restrict__ vt,
    const int* __restrict__ mask, short* __restrict__ ctx)
{
  const int t = threadIdx.x;
  const int lane = t & 63, wave = t >> 6;
  const int l15 = lane & 15, lg = lane >> 4;

  const int bid0 = blockIdx.x + gridDim.x * (blockIdx.y + gridDim.y * blockIdx.z);
  const int lid = (bid0 & 7) * 64 + (bid0 >> 3);
  const int qb = lid & 15, h = (lid >> 4) & 15, b = lid >> 8;

  __shared__ __align__(16) short Ks[2][64 * 64];
  __shared__ __align__(16) short Vs[2][64 * 64];
  __shared__ __align__(16) short p_lds[8][16 * PSTR];
  __shared__ int allv_lds;
  short* prow = p_lds[wave];

  // block-uniform mask check: 512 threads x int4 cover all 2048 keys of batch b
  if (t == 0) allv_lds = 1;
  __syncthreads();
  {
    const int4 mv = *(const int4*)&mask[b * TT + t * 4];
    if (!(mv.x && mv.y && mv.z && mv.w)) allv_lds = 0;   // benign race: all writers store 0
  }
  __syncthreads();
  const bool allv = (allv_lds != 0);

  const short* qp = qkv + ((size_t)(b * TT + qb * 128 + wave * 16 + l15)) * 3072 + h * 64;
  const short8v qf0 = scale8(*(const short8v*)(qp + lg * 8));
  const short8v qf1 = scale8(*(const short8v*)(qp + 32 + lg * 8));

  const short* kbase = qkv + (size_t)b * TT * 3072 + 1024 + h * 64;
  const short* vtb   = vt + ((size_t)(b * HH + h)) * 64 * TT;

  const int srow = lane >> 3;
  const int scol = (lane & 7) ^ (srow & 7);

  float m_run = -3e30f, l_run = 0.f;
  floatx4 zero = {0.f, 0.f, 0.f, 0.f};
  floatx4 o[4];
#pragma unroll
  for (int n = 0; n < 4; ++n) o[n] = zero;

#define STAGE_KV(bufi, kb_) do {                                             \
    const int r_ = wave * 8 + srow;                                          \
    gload_lds16(kbase + (size_t)((kb_) * 64 + r_) * 3072 + scol * 8,         \
                &Ks[bufi][wave * 512]);                                      \
    gload_lds16(vtb + (size_t)r_ * TT + (kb_) * 64 + scol * 8,               \
                &Vs[bufi][wave * 512]);                                      \
  } while (0)

#define FLASH_LOOP(MASKED)                                                        \
  {                                                                               \
    STAGE_KV(0, 0);                                                               \
    int buf = 0;                                                                  \
    for (int kb = 0; kb < NT; ++kb) {                                             \
      if (kb + 1 < NT) {                                                          \
        STAGE_KV(buf ^ 1, kb + 1);                                                \
        asm volatile("s_waitcnt vmcnt(2)" ::: "memory");                          \
      } else {                                                                    \
        asm volatile("s_waitcnt vmcnt(0)" ::: "memory");                          \
      }                                                                           \
      __builtin_amdgcn_s_barrier();                                               \
                                                                                  \
      float cm[4][4];                                                             \
      if (MASKED) {                                                               \
        _Pragma("unroll")                                                         \
        for (int n = 0; n < 4; ++n) {                                             \
          const int4 mv = *(const int4*)&mask[b * TT + kb * 64 + n * 16 + lg * 4];\
          cm[n][0] = mv.x ? 0.f : -1.5e30f; cm[n][1] = mv.y ? 0.f : -1.5e30f;     \
          cm[n][2] = mv.z ? 0.f : -1.5e30f; cm[n][3] = mv.w ? 0.f : -1.5e30f;     \
        }                                                                         \
      }                                                                           \
                                                                                  \
      floatx4 s[4];                                                               \
      _Pragma("unroll")                                                           \
      for (int n = 0; n < 4; ++n) {                                               \
        const int row = n * 16 + l15;                                             \
        const int ch0 = lg ^ (row & 7);                                           \
        const int ch1 = (lg + 4) ^ (row & 7);                                     \
        const short8v kf0 = *(const short8v*)&Ks[buf][row * 64 + ch0 * 8];        \
        const short8v kf1 = *(const short8v*)&Ks[buf][row * 64 + ch1 * 8];        \
        floatx4 a = zero;                                                         \
        a = __builtin_amdgcn_mfma_f32_16x16x32_bf16(kf0, qf0, a, 0, 0, 0);        \
        a = __builtin_amdgcn_mfma_f32_16x16x32_bf16(kf1, qf1, a, 0, 0, 0);        \
        s[n] = a;                                                                 \
      }                                                                           \
      if (MASKED) {                                                               \
        _Pragma("unroll")                                                         \
        for (int n = 0; n < 4; ++n)                                               \
          _Pragma("unroll")                                                       \
          for (int jj = 0; jj < 4; ++jj) s[n][jj] += cm[n][jj];                   \
      }                                                                           \
                                                                                  \
      const float t0 = max3f(s[0][0], s[0][1], s[0][2]);                          \
      const float t1 = max3f(s[0][3], s[1][0], s[1][1]);                          \
      const float t2 = max3f(s[1][2], s[1][3], s[2][0]);                          \
      const float t3 = max3f(s[2][1], s[2][2], s[2][3]);                          \
      const float t4 = max3f(s[3][0], s[3][1], s[3][2]);                          \
      float mx = fmaxf(max3f(t0, t1, t2), max3f(t3, t4, s[3][3]));                \
      mx = fmaxf(mx, __shfl_xor(mx, 16, 64));                                     \
      mx = fmaxf(mx, __shfl_xor(mx, 32, 64));                                     \
                                                                                  \
      const bool defer = __all(mx - m_run <= 11.5f);                              \
      const float mnew = defer ? m_run : fmaxf(m_run, mx);                        \
      float ps[4];                                                                \
      _Pragma("unroll")                                                           \
      for (int n = 0; n < 4; ++n) {                                               \
        s[n][0] = fexp2(s[n][0] - mnew);                                          \
        s[n][1] = fexp2(s[n][1] - mnew);                                          \
        s[n][2] = fexp2(s[n][2] - mnew);                                          \
        s[n][3] = fexp2(s[n][3] - mnew);                                          \
        ps[n] = (s[n][0] + s[n][1]) + (s[n][2] + s[n][3]);                        \
      }                                                                           \
      float sum = (ps[0] + ps[1]) + (ps[2] + ps[3]);                              \
      sum += __shfl_xor(sum, 16, 64);                                             \
      sum += __shfl_xor(sum, 32, 64);                                             \
      if (defer) {                                                                \
        l_run += sum;                                                             \
      } else {                                                                    \
        const float al = fexp2(m_run - mnew);                                     \
        l_run = l_run * al + sum;                                                 \
        m_run = mnew;                                                             \
        float alo[4];                                                             \
        _Pragma("unroll")                                                         \
        for (int jj = 0; jj < 4; ++jj) alo[jj] = __shfl(al, lg * 4 + jj, 16);     \
        _Pragma("unroll")                                                         \
        for (int n = 0; n < 4; ++n)                                               \
          _Pragma("unroll")                                                       \
          for (int jj = 0; jj < 4; ++jj) o[n][jj] *= alo[jj];                     \
      }                                                                           \
                                                                                  \
      _Pragma("unroll")                                                           \
      for (int n = 0; n < 4; ++n) {                                               \
        const unsigned u0 = pack2bf(s[n][0], s[n][1]);                            \
        const unsigned u1 = pack2bf(s[n][2], s[n][3]);                            \
        *(uint2*)&prow[l15 * PSTR + n * 16 + lg * 4] = make_uint2(u0, u1);        \
      }                                                                           \
      const short8v pf0 = *(const short8v*)&prow[l15 * PSTR + lg * 8];            \
      const short8v pf1 = *(const short8v*)&prow[l15 * PSTR + 32 + lg * 8];       \
                                                                                  \
      _Pragma("unroll")                                                           \
      for (int n = 0; n < 4; ++n) {                                               \
        const int row = n * 16 + l15;                                             \
        const int ch0 = lg ^ (row & 7);                                           \
        const int ch1 = (lg + 4) ^ (row & 7);                                     \
        const short8v vf0 = *(const short8v*)&Vs[buf][row * 64 + ch0 * 8];        \
        const short8v vf1 = *(const short8v*)&Vs[buf][row * 64 + ch1 * 8];        \
        o[n] = __builtin_amdgcn_mfma_f32_16x16x32_bf16(pf0, vf0, o[n], 0, 0, 0);  \
        o[n] = __builtin_amdgcn_mfma_f32_16x16x32_bf16(pf1, vf1, o[n], 0, 0, 0);  \
      }                                                                           \
      asm volatile("" ::: "memory");                                              \
      __builtin_amdgcn_s_barrier();                                               \
      buf ^= 1;                                                                   \
    }                                                                             \
  }

  if (allv) FLASH_LOOP(0)
  else      FLASH_LOOP(1)
#undef FLASH_LOOP
#undef STAGE_KV

#pragma unroll
  for (int jj = 0; jj < 4; ++jj) {
    const float inv = 1.f / __shfl(l_run, lg * 4 + jj, 16);
    const int row = qb * 128 + wave * 16 + lg * 4 + jj;
#pragma unroll
    for (int n = 0; n < 4; ++n)
      ctx[((size_t)(b * TT + row)) * DD + h * 64 + n * 16 + l15] = f2bf(o[n][jj] * inv);
  }
}

// ---------------- fused residual-add + LayerNorm; bf16 residual stream
// XF32: residual input is fp32 (first layer reads x); OUTF: write fp32 (final LN)
template<int XF32, int OUTF>
__global__ __launch_bounds__(256) void add_ln(
    const float* __restrict__ xrf, const short* __restrict__ xrb,
    const short* __restrict__ add,
    const float* __restrict__ g, const float* __restrict__ bb,
    float* __restrict__ outf, short* __restrict__ outb)
{
  const int row = blockIdx.x, t = threadIdx.x;
  const int lane = t & 63, wave = t >> 6;
  float y[4];
  if (XF32) {
    const float4 xv = *(const float4*)(xrf + (size_t)row * DD + t * 4);
    y[0] = xv.x; y[1] = xv.y; y[2] = xv.z; y[3] = xv.w;
  } else {
    const short4v xv = *(const short4v*)(xrb + (size_t)row * DD + t * 4);
#pragma unroll
    for (int i = 0; i < 4; ++i) y[i] = bf2f(xv[i]);
  }
  if (add) {
    const short4v av = *(const short4v*)(add + (size_t)row * DD + t * 4);
#pragma unroll
    for (int i = 0; i < 4; ++i) y[i] += bf2f(av[i]);
  }
  float s = y[0] + y[1] + y[2] + y[3];
  float ss = y[0]*y[0] + y[1]*y[1] + y[2]*y[2] + y[3]*y[3];
#pragma unroll
  for (int off = 32; off >= 1; off >>= 1) {
    s  += __shfl_xor(s, off, 64);
    ss += __shfl_xor(ss, off, 64);
  }
  __shared__ float red[2][4];
  if (lane == 0) { red[0][wave] = s; red[1][wave] = ss; }
  __syncthreads();
  s  = red[0][0] + red[0][1] + red[0][2] + red[0][3];
  ss = red[1][0] + red[1][1] + red[1][2] + red[1][3];
  const float mu = s * (1.f / DD);
  const float var = ss * (1.f / DD) - mu * mu;
  const float rs = rsqrtf(var + 1e-5f);
  const float4 gv = *(const float4*)(g + t * 4);
  const float4 bv = *(const float4*)(bb + t * 4);
  float o[4];
  o[0] = (y[0] - mu) * rs * gv.x + bv.x;
  o[1] = (y[1] - mu) * rs * gv.y + bv.y;
  o[2] = (y[2] - mu) * rs * gv.z + bv.z;
  o[3] = (y[3] - mu) * rs * gv.w + bv.w;
  if (OUTF) {
    *(float4*)(outf + (size_t)row * DD + t * 4) = make_float4(o[0], o[1], o[2], o[3]);
  } else {
    short4v ov;
#pragma unroll
    for (int i = 0; i < 4; ++i) ov[i] = f2bf(o[i]);
    *(short4v*)(outb + (size_t)row * DD + t * 4) = ov;
  }
}

// ---------------- x (fp32) -> xr (bf16); first add_ln reads x (fp32) directly
__global__ __launch_bounds__(256) void cast_in(
    const float* __restrict__ x, short* __restrict__ xr)
{
  const int i = (blockIdx.x * 256 + threadIdx.x) * 4;
  const float4 v = *(const float4*)(x + i);
  short4v o; o[0] = f2bf(v.x); o[1] = f2bf(v.y); o[2] = f2bf(v.z); o[3] = f2bf(v.w);
  *(short4v*)(xr + i) = o;
}

extern "C" void kernel_launch(void* const* d_in, const int* in_sizes, int n_in,
                              void* d_out, int out_size, void* d_ws, size_t ws_size,
                              hipStream_t stream) {
  const float* x   = (const float*)d_in[0];
  const int* mask  = (const int*)d_in[1];
  const float* Wq  = (const float*)d_in[2];
  const float* bq  = (const float*)d_in[3];
  const float* Wk  = (const float*)d_in[4];
  const float* bk  = (const float*)d_in[5];
  const float* Wv  = (const float*)d_in[6];
  const float* bv  = (const float*)d_in[7];
  const float* Wo  = (const float*)d_in[8];
  const float* bo  = (const float*)d_in[9];
  const float* f1w = (const float*)d_in[10];
  const float* f1b = (const float*)d_in[11];
  const float* f2w = (const float*)d_in[12];
  const float* f2b = (const float*)d_in[13];
  const float* l1g = (const float*)d_in[14];
  const float* l1b = (const float*)d_in[15];
  const float* l2g = (const float*)d_in[16];
  const float* l2b = (const float*)d_in[17];
  const float* lfg = (const float*)d_in[18];
  const float* lfb = (const float*)d_in[19];
  float* out = (float*)d_out;   // reference output dtype is float32

  char* ws = (char*)d_ws;
  const size_t MB = 1u << 20;
  short* xr   = (short*)(ws);              // 0-8   bf16 residual stream (also GEMM A)
  short* qkv  = (short*)(ws + 8 * MB);     // 8-32  fused QKV [4096][3072]
  short* vt_  = (short*)(ws + 32 * MB);    // 32-40 V^T (written by gemm256 epilogue)
  short* ctx  = (short*)(ws + 40 * MB);    // 40-48 attention context
  short* tmp  = (short*)(ws + 48 * MB);    // 48-56 attn_out / ff_out
  short* wbuf = (short*)(ws + 56 * MB);    // 56-81.2 layer weights (bf16)
  short* hb   = qkv;                       // FFN hidden 8-40MB (qkv+vt dead after flash)

  cast_in<<<(MM * DD) / (256 * 4), 256, 0, stream>>>(x, xr);

  for (int l = 0; l < LL; ++l) {
    cast_layer<<<WTOT / (256 * 4), 256, 0, stream>>>(
        Wq + (size_t)l * SEG, Wk + (size_t)l * SEG, Wv + (size_t)l * SEG, Wo + (size_t)l * SEG,
        f1w + (size_t)l * DFF * DD, f2w + (size_t)l * DD * DFF, wbuf);
    const short* wqkv_b = wbuf;                       // [3072][1024]
    const short* wo_b   = wbuf + 3 * SEG;
    const short* f1_b   = wbuf + 4 * SEG;
    const short* f2_b   = wbuf + 4 * SEG + DFF * DD;

    gemm256<0,1><<<dim3(3072 / 256, MM / 256), 512, 0, stream>>>(
        xr, wqkv_b, bq + l * DD, bk + l * DD, bv + l * DD, qkv, vt_, MM, 3072, DD);
    flash_attn<<<dim3(TT / 128, HH, BB), 512, 0, stream>>>(qkv, vt_, mask, ctx);
    gemm128<0><<<dim3(DD / 128, MM / 128), 512, 0, stream>>>(ctx, wo_b, bo + l * DD, tmp, MM, DD, DD);
    if (l == 0)
      add_ln<1,0><<<MM, 256, 0, stream>>>(x, nullptr, tmp, l1g, l1b, nullptr, xr);
    else
      add_ln<0,0><<<MM, 256, 0, stream>>>(nullptr, xr, tmp, l1g + l * DD, l1b + l * DD, nullptr, xr);
    gemm256<1,0><<<dim3(DFF / 256, MM / 256), 512, 0, stream>>>(
        xr, f1_b, f1b + l * DFF, nullptr, nullptr, hb, nullptr, MM, DFF, DD);
    gemm128<0><<<dim3(DD / 128, MM / 128), 512, 0, stream>>>(hb, f2_b, f2b + l * DD, tmp, MM, DD, DFF);
    add_ln<0,0><<<MM, 256, 0, stream>>>(nullptr, xr, tmp, l2g + l * DD, l2b + l * DD, nullptr, xr);
  }
  add_ln<0,1><<<MM, 256, 0, stream>>>(nullptr, xr, nullptr, lfg, lfb, out, nullptr);
}